// Round 3
// baseline (421.352 us; speedup 1.0000x reference)
//
#include <hip/hip_runtime.h>
#include <hip/hip_bf16.h>

typedef __attribute__((ext_vector_type(4))) float floatx4;
typedef __attribute__((ext_vector_type(8))) short shortx8;

struct bf4 { __hip_bfloat16 h[4]; };  // 8-byte pack for bf16 stores
union U8 { shortx8 v; __hip_bfloat16 h[8]; };

__device__ __forceinline__ void async_copy16(const __hip_bfloat16* g, __hip_bfloat16* l) {
  __builtin_amdgcn_global_load_lds((__attribute__((address_space(1))) void*)g,
                                   (__attribute__((address_space(3))) void*)l,
                                   16, 0, 0);
}

// ---------------------------------------------------------------------------
// fp32 -> bf16 cast, 4 elems/thread
// ---------------------------------------------------------------------------
__global__ __launch_bounds__(256) void cast_kernel(const float* __restrict__ in,
                                                   __hip_bfloat16* __restrict__ out) {
  const int i = blockIdx.x * 256 + threadIdx.x;
  const float4 v = ((const float4*)in)[i];
  bf4 o4;
  o4.h[0] = __float2bfloat16(v.x);
  o4.h[1] = __float2bfloat16(v.y);
  o4.h[2] = __float2bfloat16(v.z);
  o4.h[3] = __float2bfloat16(v.w);
  *(bf4*)(out + (size_t)i * 4) = o4;
}

// ---------------------------------------------------------------------------
// GEMM C[M,N] = A[M,K] * B[N,K]^T  (bf16 in, fp32 acc), m97-style 128x128 tile
// EPI: 0 = +bias -> bf16 out; 1 = +bias, gelu -> bf16 out; 2 = +bias +resid -> f32 out
// ---------------------------------------------------------------------------
template<int EPI>
__global__ __launch_bounds__(256) void gemm_bt(
    const __hip_bfloat16* __restrict__ A,   // [M,K]
    const __hip_bfloat16* __restrict__ B,   // [N,K]
    const float* __restrict__ bias,         // [N]
    const float* __restrict__ resid,        // [M,N] (EPI==2)
    __hip_bfloat16* __restrict__ outb,      // EPI 0/1
    float* __restrict__ outf,               // EPI 2
    int M, int N, int K)
{
  __shared__ __align__(16) __hip_bfloat16 As[128 * 32];
  __shared__ __align__(16) __hip_bfloat16 Bs[128 * 32];
  const int tid  = threadIdx.x;
  const int lane = tid & 63;
  const int wave = tid >> 6;
  const int wr = wave >> 1, wc = wave & 1;
  const long bm = (long)blockIdx.y * 128, bn = (long)blockIdx.x * 128;

  const int srow = tid >> 2;
  const int scol = (tid & 3) << 3;
  const __hip_bfloat16* Ag0 = A + (bm + srow) * (long)K + scol;
  const __hip_bfloat16* Bg0 = B + (bn + srow) * (long)K + scol;
  const long rstride = 64l * K;
  __hip_bfloat16* As0 = &As[tid * 8];
  __hip_bfloat16* Bs0 = &Bs[tid * 8];

  const int fr = lane & 15;
  const int fq = lane >> 4;

  const floatx4 zero = {0.f, 0.f, 0.f, 0.f};
  floatx4 acc[4][4];
#pragma unroll
  for (int mi = 0; mi < 4; ++mi)
#pragma unroll
    for (int ni = 0; ni < 4; ++ni) acc[mi][ni] = zero;

  for (int k0 = 0; k0 < K; k0 += 32) {
    async_copy16(Ag0 + k0,           As0);
    async_copy16(Ag0 + k0 + rstride, As0 + 64 * 32);
    async_copy16(Bg0 + k0,           Bs0);
    async_copy16(Bg0 + k0 + rstride, Bs0 + 64 * 32);
    __syncthreads();
    shortx8 afr[4], bfr[4];
#pragma unroll
    for (int i = 0; i < 4; ++i) {
      afr[i] = *(const shortx8*)&As[(wr * 64 + i * 16 + fr) * 32 + fq * 8];
      bfr[i] = *(const shortx8*)&Bs[(wc * 64 + i * 16 + fr) * 32 + fq * 8];
    }
#pragma unroll
    for (int mi = 0; mi < 4; ++mi)
#pragma unroll
      for (int ni = 0; ni < 4; ++ni)
        acc[mi][ni] = __builtin_amdgcn_mfma_f32_16x16x32_bf16(afr[mi], bfr[ni], acc[mi][ni], 0, 0, 0);
    __syncthreads();
  }

  // epilogue: C/D layout col = lane&15, row = (lane>>4)*4 + reg
#pragma unroll
  for (int mi = 0; mi < 4; ++mi) {
#pragma unroll
    for (int ni = 0; ni < 4; ++ni) {
      const long col = bn + wc * 64 + ni * 16 + fr;
      const float bv = bias[col];
#pragma unroll
      for (int r = 0; r < 4; ++r) {
        const long row = bm + wr * 64 + mi * 16 + fq * 4 + r;
        float v = acc[mi][ni][r] + bv;
        if (EPI == 1) v = 0.5f * v * (1.0f + erff(v * 0.70710678118f));
        const size_t idx = (size_t)row * N + col;
        if (EPI == 2) outf[idx] = v + resid[idx];
        else          outb[idx] = __float2bfloat16(v);
      }
    }
  }
}

// ---------------------------------------------------------------------------
// V transpose: qkv v-part [token, h*64+d] -> vt[(bh*64+d)*1024 + token]
// ---------------------------------------------------------------------------
__global__ __launch_bounds__(256) void transpose_v_kernel(
    const __hip_bfloat16* __restrict__ qkv, __hip_bfloat16* __restrict__ vt)
{
  const int bh = blockIdx.y;          // 0..63
  const int tt = blockIdx.x;          // 0..15 token tiles of 64
  const int b = bh >> 4, h = bh & 15;
  __shared__ __hip_bfloat16 tile[64][65];
  const int tid = threadIdx.x;
  const int r = tid >> 2;             // 0..63
  const int c = (tid & 3) << 4;       // 0,16,32,48
  const __hip_bfloat16* src = qkv + (size_t)(b * 1024 + tt * 64 + r) * 3072 + 2048 + h * 64 + c;
  U8 u0, u1;
  u0.v = *(const shortx8*)src;
  u1.v = *(const shortx8*)(src + 8);
#pragma unroll
  for (int j = 0; j < 8; ++j) { tile[r][c + j] = u0.h[j]; tile[r][c + 8 + j] = u1.h[j]; }
  __syncthreads();
  U8 w0, w1;
#pragma unroll
  for (int j = 0; j < 8; ++j) { w0.h[j] = tile[c + j][r]; w1.h[j] = tile[c + 8 + j][r]; }
  __hip_bfloat16* dst = vt + ((size_t)bh * 64 + r) * 1024 + tt * 64 + c;
  *(shortx8*)dst       = w0.v;
  *(shortx8*)(dst + 8) = w1.v;
}

// ---------------------------------------------------------------------------
// Banded-causal flash attention. One wave per (b,h,q-tile of 16).
// Q/K read from qkv bf16; V from pre-transposed vt. Softmax in exp2 domain.
// ---------------------------------------------------------------------------
__global__ __launch_bounds__(256) void attn_kernel(
    const __hip_bfloat16* __restrict__ qkv,  // [4096, 3072]
    const __hip_bfloat16* __restrict__ vt,   // [64*64, 1024]
    __hip_bfloat16* __restrict__ ctx)        // [4096, 1024]
{
  const int wave = threadIdx.x >> 6;
  const int lane = threadIdx.x & 63;
  const int gw = blockIdx.x * 4 + wave;   // 0..4095
  const int qt = gw & 63;
  const int bh = gw >> 6;
  const int b = bh >> 4, h = bh & 15;
  const int fr = lane & 15, fq = lane >> 4;
  const int q0 = qt << 4;

  __shared__ __align__(16) __hip_bfloat16 Plds[4][16 * 32];
  __hip_bfloat16* Pw = Plds[wave];

  const __hip_bfloat16* qrow = qkv + (size_t)(b * 1024 + q0 + fr) * 3072 + h * 64;
  const shortx8 aq0 = *(const shortx8*)(qrow + fq * 8);
  const shortx8 aq1 = *(const shortx8*)(qrow + 32 + fq * 8);

  const float SC = 0.125f * 1.44269504088896f;  // scale * log2(e)
  float m_r[4] = {-1e30f, -1e30f, -1e30f, -1e30f};
  float l_r[4] = {0.f, 0.f, 0.f, 0.f};
  const floatx4 zero = {0.f, 0.f, 0.f, 0.f};
  floatx4 o[4];
#pragma unroll
  for (int nd = 0; nd < 4; ++nd) o[nd] = zero;

  // BUGFIX (round 2): earliest visible key for this q-tile is q0-255 (query q0),
  // NOT q0-240 (that is the mask-needed bound, for query q0+15). Using 240 here
  // dropped up to 15 visible keys per tile -> deterministic absmax 0.26.
  const int kt0 = (q0 >= 255) ? ((q0 - 255) >> 5) : 0;
  const int kt1 = (q0 + 15) >> 5;
  for (int kt = kt0; kt <= kt1; ++kt) {
    const int kbase = kt << 5;
    const __hip_bfloat16* krow0 = qkv + (size_t)(b * 1024 + kbase + fr) * 3072 + 1024 + h * 64;
    const __hip_bfloat16* krow1 = krow0 + 16 * 3072;
    const shortx8 bk00 = *(const shortx8*)(krow0 + fq * 8);
    const shortx8 bk01 = *(const shortx8*)(krow0 + 32 + fq * 8);
    const shortx8 bk10 = *(const shortx8*)(krow1 + fq * 8);
    const shortx8 bk11 = *(const shortx8*)(krow1 + 32 + fq * 8);
    floatx4 s0 = zero, s1 = zero;
    s0 = __builtin_amdgcn_mfma_f32_16x16x32_bf16(aq0, bk00, s0, 0, 0, 0);
    s0 = __builtin_amdgcn_mfma_f32_16x16x32_bf16(aq1, bk01, s0, 0, 0, 0);
    s1 = __builtin_amdgcn_mfma_f32_16x16x32_bf16(aq0, bk10, s1, 0, 0, 0);
    s1 = __builtin_amdgcn_mfma_f32_16x16x32_bf16(aq1, bk11, s1, 0, 0, 0);
#pragma unroll
    for (int r = 0; r < 4; ++r) { s0[r] *= SC; s1[r] *= SC; }
    if (kbase + 31 > q0 || kbase < q0 - 240) {   // wave-uniform branch (mask bound: query q0+15)
#pragma unroll
      for (int r = 0; r < 4; ++r) {
        const int tq = q0 + fq * 4 + r;
        const int j0 = kbase + fr;
        const int j1 = j0 + 16;
        if (j0 > tq || j0 < tq - 255) s0[r] = -3e38f;
        if (j1 > tq || j1 < tq - 255) s1[r] = -3e38f;
      }
    }
#pragma unroll
    for (int r = 0; r < 4; ++r) {
      float vmax = fmaxf(s0[r], s1[r]);
      vmax = fmaxf(vmax, __shfl_xor(vmax, 1));
      vmax = fmaxf(vmax, __shfl_xor(vmax, 2));
      vmax = fmaxf(vmax, __shfl_xor(vmax, 4));
      vmax = fmaxf(vmax, __shfl_xor(vmax, 8));
      const float mnew = fmaxf(m_r[r], vmax);
      const float alpha = exp2f(m_r[r] - mnew);
      const float p0 = exp2f(s0[r] - mnew);
      const float p1 = exp2f(s1[r] - mnew);
      m_r[r] = mnew;
      float ps = p0 + p1;
      ps += __shfl_xor(ps, 1);
      ps += __shfl_xor(ps, 2);
      ps += __shfl_xor(ps, 4);
      ps += __shfl_xor(ps, 8);
      l_r[r] = l_r[r] * alpha + ps;
      o[0][r] *= alpha; o[1][r] *= alpha; o[2][r] *= alpha; o[3][r] *= alpha;
      Pw[(fq * 4 + r) * 32 + fr]      = __float2bfloat16(p0);
      Pw[(fq * 4 + r) * 32 + 16 + fr] = __float2bfloat16(p1);
    }
    // P (C-layout) -> A-layout via LDS round trip (in-order DS pipe per wave;
    // waitcnt keeps compiler from reordering the cross-lane read before the write)
    asm volatile("s_waitcnt lgkmcnt(0)" ::: "memory");
    const shortx8 ap = *(const shortx8*)&Pw[fr * 32 + fq * 8];
#pragma unroll
    for (int nd = 0; nd < 4; ++nd) {
      const shortx8 bv = *(const shortx8*)&vt[((size_t)bh * 64 + nd * 16 + fr) * 1024 + kbase + fq * 8];
      o[nd] = __builtin_amdgcn_mfma_f32_16x16x32_bf16(ap, bv, o[nd], 0, 0, 0);
    }
    asm volatile("s_waitcnt lgkmcnt(0)" ::: "memory");
  }
#pragma unroll
  for (int nd = 0; nd < 4; ++nd)
#pragma unroll
    for (int r = 0; r < 4; ++r)
      ctx[(size_t)(b * 1024 + q0 + fq * 4 + r) * 1024 + h * 64 + nd * 16 + fr] =
          __float2bfloat16(o[nd][r] / l_r[r]);
}

// ---------------------------------------------------------------------------
// LayerNorm over C=1024, one block per row. WB: also emit bf16 copy.
// ---------------------------------------------------------------------------
template<int WB>
__global__ __launch_bounds__(256) void ln_kernel(
    const float* __restrict__ in, const float* __restrict__ g, const float* __restrict__ be,
    float* __restrict__ outf, __hip_bfloat16* __restrict__ outb)
{
  const int row = blockIdx.x;
  const int tid = threadIdx.x;
  const float4 v = ((const float4*)(in + (size_t)row * 1024))[tid];
  float s  = v.x + v.y + v.z + v.w;
  float ss = v.x * v.x + v.y * v.y + v.z * v.z + v.w * v.w;
#pragma unroll
  for (int off = 1; off < 64; off <<= 1) {
    s  += __shfl_xor(s, off);
    ss += __shfl_xor(ss, off);
  }
  __shared__ float red[8];
  if ((tid & 63) == 0) { red[tid >> 6] = s; red[4 + (tid >> 6)] = ss; }
  __syncthreads();
  s  = red[0] + red[1] + red[2] + red[3];
  ss = red[4] + red[5] + red[6] + red[7];
  const float mu = s * (1.0f / 1024.0f);
  const float rs = rsqrtf(ss * (1.0f / 1024.0f) - mu * mu + 1e-5f);
  const float4 gg = ((const float4*)g)[tid];
  const float4 bb = ((const float4*)be)[tid];
  float4 y;
  y.x = (v.x - mu) * rs * gg.x + bb.x;
  y.y = (v.y - mu) * rs * gg.y + bb.y;
  y.z = (v.z - mu) * rs * gg.z + bb.z;
  y.w = (v.w - mu) * rs * gg.w + bb.w;
  ((float4*)(outf + (size_t)row * 1024))[tid] = y;
  if (WB) {
    bf4 o4;
    o4.h[0] = __float2bfloat16(y.x);
    o4.h[1] = __float2bfloat16(y.y);
    o4.h[2] = __float2bfloat16(y.z);
    o4.h[3] = __float2bfloat16(y.w);
    *(bf4*)(outb + (size_t)row * 1024 + tid * 4) = o4;
  }
}

// ---------------------------------------------------------------------------
extern "C" void kernel_launch(void* const* d_in, const int* in_sizes, int n_in,
                              void* d_out, int out_size, void* d_ws, size_t ws_size,
                              hipStream_t stream) {
  const float* x    = (const float*)d_in[0];
  const float* Wqkv = (const float*)d_in[1];
  const float* bqkv = (const float*)d_in[2];
  const float* Wo   = (const float*)d_in[3];
  const float* bo   = (const float*)d_in[4];
  const float* W1   = (const float*)d_in[5];
  const float* b1   = (const float*)d_in[6];
  const float* W2   = (const float*)d_in[7];
  const float* b2   = (const float*)d_in[8];
  const float* g1   = (const float*)d_in[9];
  const float* be1  = (const float*)d_in[10];
  const float* g2   = (const float*)d_in[11];
  const float* be2  = (const float*)d_in[12];

  char* ws = (char*)d_ws;
  size_t off = 0;
  auto alloc = [&](size_t bytes) -> void* {
    void* p = ws + off;
    off += (bytes + 255) & ~(size_t)255;
    return p;
  };
  __hip_bfloat16* wbuf = (__hip_bfloat16*)alloc(8u << 20);       // reused weight buf
  __hip_bfloat16* xb   = (__hip_bfloat16*)alloc(8388608);        // x bf16
  __hip_bfloat16* qkvb = (__hip_bfloat16*)alloc(25165824);       // [4096,3072]
  __hip_bfloat16* vtb  = (__hip_bfloat16*)alloc(8388608);        // V transposed
  __hip_bfloat16* ctxb = (__hip_bfloat16*)alloc(8388608);        // attn context
  float*          res1 = (float*)alloc(16777216);                // x + attn_out
  float*          x1f  = (float*)alloc(16777216);                // LN1 out f32
  __hip_bfloat16* x1b  = (__hip_bfloat16*)alloc(8388608);        // LN1 out bf16
  __hip_bfloat16* hb   = (__hip_bfloat16*)alloc(33554432);       // gelu(ffn1) [4096,4096]
  float*          res2 = (float*)alloc(16777216);                // x1 + ffn_out
  (void)ws_size; (void)in_sizes; (void)n_in; (void)out_size;

  // 1. casts + QKV projection
  cast_kernel<<<4096, 256, 0, stream>>>(x, xb);
  cast_kernel<<<3072, 256, 0, stream>>>(Wqkv, wbuf);
  gemm_bt<0><<<dim3(24, 32), 256, 0, stream>>>(xb, wbuf, bqkv, nullptr, qkvb, nullptr,
                                               4096, 3072, 1024);
  // 2. attention
  transpose_v_kernel<<<dim3(16, 64), 256, 0, stream>>>(qkvb, vtb);
  attn_kernel<<<1024, 256, 0, stream>>>(qkvb, vtb, ctxb);
  // 3. output projection + residual, LN1
  cast_kernel<<<1024, 256, 0, stream>>>(Wo, wbuf);
  gemm_bt<2><<<dim3(8, 32), 256, 0, stream>>>(ctxb, wbuf, bo, x, nullptr, res1,
                                              4096, 1024, 1024);
  ln_kernel<1><<<4096, 256, 0, stream>>>(res1, g1, be1, x1f, x1b);
  // 4. FFN
  cast_kernel<<<4096, 256, 0, stream>>>(W1, wbuf);
  gemm_bt<1><<<dim3(32, 32), 256, 0, stream>>>(x1b, wbuf, b1, nullptr, hb, nullptr,
                                               4096, 4096, 1024);
  cast_kernel<<<4096, 256, 0, stream>>>(W2, wbuf);
  gemm_bt<2><<<dim3(8, 32), 256, 0, stream>>>(hb, wbuf, b2, x1f, nullptr, res2,
                                              4096, 1024, 4096);
  ln_kernel<0><<<4096, 256, 0, stream>>>(res2, g2, be2, (float*)d_out, nullptr);
}

// Round 4
// 398.348 us; speedup vs baseline: 1.0577x; 1.0577x over previous
//
#include <hip/hip_runtime.h>
#include <hip/hip_bf16.h>

typedef __attribute__((ext_vector_type(4))) float floatx4;
typedef __attribute__((ext_vector_type(8))) short shortx8;

struct bf4 { __hip_bfloat16 h[4]; };  // 8-byte pack for bf16 stores
union U8 { shortx8 v; __hip_bfloat16 h[8]; };

__device__ __forceinline__ void async_copy16(const __hip_bfloat16* g, __hip_bfloat16* l) {
  __builtin_amdgcn_global_load_lds((__attribute__((address_space(1))) void*)g,
                                   (__attribute__((address_space(3))) void*)l,
                                   16, 0, 0);
}

// ---------------------------------------------------------------------------
// fp32 -> bf16 cast, 4 elems/thread
// ---------------------------------------------------------------------------
__global__ __launch_bounds__(256) void cast_kernel(const float* __restrict__ in,
                                                   __hip_bfloat16* __restrict__ out) {
  const int i = blockIdx.x * 256 + threadIdx.x;
  const float4 v = ((const float4*)in)[i];
  bf4 o4;
  o4.h[0] = __float2bfloat16(v.x);
  o4.h[1] = __float2bfloat16(v.y);
  o4.h[2] = __float2bfloat16(v.z);
  o4.h[3] = __float2bfloat16(v.w);
  *(bf4*)(out + (size_t)i * 4) = o4;
}

// ---------------------------------------------------------------------------
// GEMM C[M,N] = A[M,K] * B[N,K]^T  (bf16 in, fp32 acc), m97-style 128x128 tile
// EPI: 0 = +bias -> bf16 out; 1 = +bias, gelu -> bf16 out
// ---------------------------------------------------------------------------
template<int EPI>
__global__ __launch_bounds__(256) void gemm_bt(
    const __hip_bfloat16* __restrict__ A,   // [M,K]
    const __hip_bfloat16* __restrict__ B,   // [N,K]
    const float* __restrict__ bias,         // [N]
    __hip_bfloat16* __restrict__ outb,
    int M, int N, int K)
{
  __shared__ __align__(16) __hip_bfloat16 As[128 * 32];
  __shared__ __align__(16) __hip_bfloat16 Bs[128 * 32];
  const int tid  = threadIdx.x;
  const int lane = tid & 63;
  const int wave = tid >> 6;
  const int wr = wave >> 1, wc = wave & 1;
  const long bm = (long)blockIdx.y * 128, bn = (long)blockIdx.x * 128;

  const int srow = tid >> 2;
  const int scol = (tid & 3) << 3;
  const __hip_bfloat16* Ag0 = A + (bm + srow) * (long)K + scol;
  const __hip_bfloat16* Bg0 = B + (bn + srow) * (long)K + scol;
  const long rstride = 64l * K;
  __hip_bfloat16* As0 = &As[tid * 8];
  __hip_bfloat16* Bs0 = &Bs[tid * 8];

  const int fr = lane & 15;
  const int fq = lane >> 4;

  const floatx4 zero = {0.f, 0.f, 0.f, 0.f};
  floatx4 acc[4][4];
#pragma unroll
  for (int mi = 0; mi < 4; ++mi)
#pragma unroll
    for (int ni = 0; ni < 4; ++ni) acc[mi][ni] = zero;

  for (int k0 = 0; k0 < K; k0 += 32) {
    async_copy16(Ag0 + k0,           As0);
    async_copy16(Ag0 + k0 + rstride, As0 + 64 * 32);
    async_copy16(Bg0 + k0,           Bs0);
    async_copy16(Bg0 + k0 + rstride, Bs0 + 64 * 32);
    __syncthreads();
    shortx8 afr[4], bfr[4];
#pragma unroll
    for (int i = 0; i < 4; ++i) {
      afr[i] = *(const shortx8*)&As[(wr * 64 + i * 16 + fr) * 32 + fq * 8];
      bfr[i] = *(const shortx8*)&Bs[(wc * 64 + i * 16 + fr) * 32 + fq * 8];
    }
#pragma unroll
    for (int mi = 0; mi < 4; ++mi)
#pragma unroll
      for (int ni = 0; ni < 4; ++ni)
        acc[mi][ni] = __builtin_amdgcn_mfma_f32_16x16x32_bf16(afr[mi], bfr[ni], acc[mi][ni], 0, 0, 0);
    __syncthreads();
  }

  // epilogue: C/D layout col = lane&15, row = (lane>>4)*4 + reg
#pragma unroll
  for (int mi = 0; mi < 4; ++mi) {
#pragma unroll
    for (int ni = 0; ni < 4; ++ni) {
      const long col = bn + wc * 64 + ni * 16 + fr;
      const float bv = bias[col];
#pragma unroll
      for (int r = 0; r < 4; ++r) {
        const long row = bm + wr * 64 + mi * 16 + fq * 4 + r;
        float v = acc[mi][ni][r] + bv;
        if (EPI == 1) v = 0.5f * v * (1.0f + erff(v * 0.70710678118f));
        outb[(size_t)row * N + col] = __float2bfloat16(v);
      }
    }
  }
}

// ---------------------------------------------------------------------------
// Split-K GEMM: each z-slice computes a raw fp32 partial over K/[gridDim.z].
// Partials land at part + z*M*N; reduction is fused into the LN kernel.
// (Split-K fixes the 1-block/CU occupancy starvation of the N=1024 GEMMs:
//  Wo and FFN2 had 256-block grids -> barrier drains stall the whole CU.)
// ---------------------------------------------------------------------------
__global__ __launch_bounds__(256) void gemm_bt_splitk(
    const __hip_bfloat16* __restrict__ A,   // [M,K]
    const __hip_bfloat16* __restrict__ B,   // [N,K]
    float* __restrict__ part,               // [splits, M, N]
    int M, int N, int K, int Klen)
{
  __shared__ __align__(16) __hip_bfloat16 As[128 * 32];
  __shared__ __align__(16) __hip_bfloat16 Bs[128 * 32];
  const int tid  = threadIdx.x;
  const int lane = tid & 63;
  const int wave = tid >> 6;
  const int wr = wave >> 1, wc = wave & 1;
  const long bm = (long)blockIdx.y * 128, bn = (long)blockIdx.x * 128;
  const int kstart = blockIdx.z * Klen;

  const int srow = tid >> 2;
  const int scol = (tid & 3) << 3;
  const __hip_bfloat16* Ag0 = A + (bm + srow) * (long)K + kstart + scol;
  const __hip_bfloat16* Bg0 = B + (bn + srow) * (long)K + kstart + scol;
  const long rstride = 64l * K;
  __hip_bfloat16* As0 = &As[tid * 8];
  __hip_bfloat16* Bs0 = &Bs[tid * 8];

  const int fr = lane & 15;
  const int fq = lane >> 4;

  const floatx4 zero = {0.f, 0.f, 0.f, 0.f};
  floatx4 acc[4][4];
#pragma unroll
  for (int mi = 0; mi < 4; ++mi)
#pragma unroll
    for (int ni = 0; ni < 4; ++ni) acc[mi][ni] = zero;

  for (int k0 = 0; k0 < Klen; k0 += 32) {
    async_copy16(Ag0 + k0,           As0);
    async_copy16(Ag0 + k0 + rstride, As0 + 64 * 32);
    async_copy16(Bg0 + k0,           Bs0);
    async_copy16(Bg0 + k0 + rstride, Bs0 + 64 * 32);
    __syncthreads();
    shortx8 afr[4], bfr[4];
#pragma unroll
    for (int i = 0; i < 4; ++i) {
      afr[i] = *(const shortx8*)&As[(wr * 64 + i * 16 + fr) * 32 + fq * 8];
      bfr[i] = *(const shortx8*)&Bs[(wc * 64 + i * 16 + fr) * 32 + fq * 8];
    }
#pragma unroll
    for (int mi = 0; mi < 4; ++mi)
#pragma unroll
      for (int ni = 0; ni < 4; ++ni)
        acc[mi][ni] = __builtin_amdgcn_mfma_f32_16x16x32_bf16(afr[mi], bfr[ni], acc[mi][ni], 0, 0, 0);
    __syncthreads();
  }

  float* outp = part + (size_t)blockIdx.z * M * N;
#pragma unroll
  for (int mi = 0; mi < 4; ++mi) {
#pragma unroll
    for (int ni = 0; ni < 4; ++ni) {
      const long col = bn + wc * 64 + ni * 16 + fr;
#pragma unroll
      for (int r = 0; r < 4; ++r) {
        const long row = bm + wr * 64 + mi * 16 + fq * 4 + r;
        outp[(size_t)row * N + col] = acc[mi][ni][r];
      }
    }
  }
}

// ---------------------------------------------------------------------------
// V transpose: qkv v-part [token, h*64+d] -> vt[(bh*64+d)*1024 + token]
// ---------------------------------------------------------------------------
__global__ __launch_bounds__(256) void transpose_v_kernel(
    const __hip_bfloat16* __restrict__ qkv, __hip_bfloat16* __restrict__ vt)
{
  const int bh = blockIdx.y;          // 0..63
  const int tt = blockIdx.x;          // 0..15 token tiles of 64
  const int b = bh >> 4, h = bh & 15;
  __shared__ __hip_bfloat16 tile[64][65];
  const int tid = threadIdx.x;
  const int r = tid >> 2;             // 0..63
  const int c = (tid & 3) << 4;       // 0,16,32,48
  const __hip_bfloat16* src = qkv + (size_t)(b * 1024 + tt * 64 + r) * 3072 + 2048 + h * 64 + c;
  U8 u0, u1;
  u0.v = *(const shortx8*)src;
  u1.v = *(const shortx8*)(src + 8);
#pragma unroll
  for (int j = 0; j < 8; ++j) { tile[r][c + j] = u0.h[j]; tile[r][c + 8 + j] = u1.h[j]; }
  __syncthreads();
  U8 w0, w1;
#pragma unroll
  for (int j = 0; j < 8; ++j) { w0.h[j] = tile[c + j][r]; w1.h[j] = tile[c + 8 + j][r]; }
  __hip_bfloat16* dst = vt + ((size_t)bh * 64 + r) * 1024 + tt * 64 + c;
  *(shortx8*)dst       = w0.v;
  *(shortx8*)(dst + 8) = w1.v;
}

// ---------------------------------------------------------------------------
// Banded-causal flash attention. One wave per (b,h,q-tile of 16).
// ---------------------------------------------------------------------------
__global__ __launch_bounds__(256) void attn_kernel(
    const __hip_bfloat16* __restrict__ qkv,  // [4096, 3072]
    const __hip_bfloat16* __restrict__ vt,   // [64*64, 1024]
    __hip_bfloat16* __restrict__ ctx)        // [4096, 1024]
{
  const int wave = threadIdx.x >> 6;
  const int lane = threadIdx.x & 63;
  const int gw = blockIdx.x * 4 + wave;   // 0..4095
  const int qt = gw & 63;
  const int bh = gw >> 6;
  const int b = bh >> 4, h = bh & 15;
  const int fr = lane & 15, fq = lane >> 4;
  const int q0 = qt << 4;

  __shared__ __align__(16) __hip_bfloat16 Plds[4][16 * 32];
  __hip_bfloat16* Pw = Plds[wave];

  const __hip_bfloat16* qrow = qkv + (size_t)(b * 1024 + q0 + fr) * 3072 + h * 64;
  const shortx8 aq0 = *(const shortx8*)(qrow + fq * 8);
  const shortx8 aq1 = *(const shortx8*)(qrow + 32 + fq * 8);

  const float SC = 0.125f * 1.44269504088896f;  // scale * log2(e)
  float m_r[4] = {-1e30f, -1e30f, -1e30f, -1e30f};
  float l_r[4] = {0.f, 0.f, 0.f, 0.f};
  const floatx4 zero = {0.f, 0.f, 0.f, 0.f};
  floatx4 o[4];
#pragma unroll
  for (int nd = 0; nd < 4; ++nd) o[nd] = zero;

  const int kt0 = (q0 >= 255) ? ((q0 - 255) >> 5) : 0;  // earliest visible key: q0-255
  const int kt1 = (q0 + 15) >> 5;
  for (int kt = kt0; kt <= kt1; ++kt) {
    const int kbase = kt << 5;
    const __hip_bfloat16* krow0 = qkv + (size_t)(b * 1024 + kbase + fr) * 3072 + 1024 + h * 64;
    const __hip_bfloat16* krow1 = krow0 + 16 * 3072;
    const shortx8 bk00 = *(const shortx8*)(krow0 + fq * 8);
    const shortx8 bk01 = *(const shortx8*)(krow0 + 32 + fq * 8);
    const shortx8 bk10 = *(const shortx8*)(krow1 + fq * 8);
    const shortx8 bk11 = *(const shortx8*)(krow1 + 32 + fq * 8);
    floatx4 s0 = zero, s1 = zero;
    s0 = __builtin_amdgcn_mfma_f32_16x16x32_bf16(aq0, bk00, s0, 0, 0, 0);
    s0 = __builtin_amdgcn_mfma_f32_16x16x32_bf16(aq1, bk01, s0, 0, 0, 0);
    s1 = __builtin_amdgcn_mfma_f32_16x16x32_bf16(aq0, bk10, s1, 0, 0, 0);
    s1 = __builtin_amdgcn_mfma_f32_16x16x32_bf16(aq1, bk11, s1, 0, 0, 0);
#pragma unroll
    for (int r = 0; r < 4; ++r) { s0[r] *= SC; s1[r] *= SC; }
    if (kbase + 31 > q0 || kbase < q0 - 240) {   // wave-uniform (mask bound: query q0+15)
#pragma unroll
      for (int r = 0; r < 4; ++r) {
        const int tq = q0 + fq * 4 + r;
        const int j0 = kbase + fr;
        const int j1 = j0 + 16;
        if (j0 > tq || j0 < tq - 255) s0[r] = -3e38f;
        if (j1 > tq || j1 < tq - 255) s1[r] = -3e38f;
      }
    }
#pragma unroll
    for (int r = 0; r < 4; ++r) {
      float vmax = fmaxf(s0[r], s1[r]);
      vmax = fmaxf(vmax, __shfl_xor(vmax, 1));
      vmax = fmaxf(vmax, __shfl_xor(vmax, 2));
      vmax = fmaxf(vmax, __shfl_xor(vmax, 4));
      vmax = fmaxf(vmax, __shfl_xor(vmax, 8));
      const float mnew = fmaxf(m_r[r], vmax);
      const float alpha = exp2f(m_r[r] - mnew);
      const float p0 = exp2f(s0[r] - mnew);
      const float p1 = exp2f(s1[r] - mnew);
      m_r[r] = mnew;
      float ps = p0 + p1;
      ps += __shfl_xor(ps, 1);
      ps += __shfl_xor(ps, 2);
      ps += __shfl_xor(ps, 4);
      ps += __shfl_xor(ps, 8);
      l_r[r] = l_r[r] * alpha + ps;
      o[0][r] *= alpha; o[1][r] *= alpha; o[2][r] *= alpha; o[3][r] *= alpha;
      Pw[(fq * 4 + r) * 32 + fr]      = __float2bfloat16(p0);
      Pw[(fq * 4 + r) * 32 + 16 + fr] = __float2bfloat16(p1);
    }
    asm volatile("s_waitcnt lgkmcnt(0)" ::: "memory");
    const shortx8 ap = *(const shortx8*)&Pw[fr * 32 + fq * 8];
#pragma unroll
    for (int nd = 0; nd < 4; ++nd) {
      const shortx8 bv = *(const shortx8*)&vt[((size_t)bh * 64 + nd * 16 + fr) * 1024 + kbase + fq * 8];
      o[nd] = __builtin_amdgcn_mfma_f32_16x16x32_bf16(ap, bv, o[nd], 0, 0, 0);
    }
    asm volatile("s_waitcnt lgkmcnt(0)" ::: "memory");
  }
#pragma unroll
  for (int nd = 0; nd < 4; ++nd)
#pragma unroll
    for (int r = 0; r < 4; ++r)
      ctx[(size_t)(b * 1024 + q0 + fq * 4 + r) * 1024 + h * 64 + nd * 16 + fr] =
          __float2bfloat16(o[nd][r] / l_r[r]);
}

// ---------------------------------------------------------------------------
// Fused split-K reduce + bias + residual + LayerNorm. One block per row.
// S partials of [4096,1024] fp32; WB: also emit bf16 copy of LN output.
// ---------------------------------------------------------------------------
template<int S, int WB>
__global__ __launch_bounds__(256) void ln_sum_kernel(
    const float* __restrict__ part,   // [S, 4096, 1024]
    const float* __restrict__ resid,  // [4096, 1024]
    const float* __restrict__ bias,   // [1024]
    const float* __restrict__ g, const float* __restrict__ be,
    float* __restrict__ outf, __hip_bfloat16* __restrict__ outb)
{
  const int row = blockIdx.x;
  const int tid = threadIdx.x;
  const size_t base = (size_t)row * 1024;
  float4 v = ((const float4*)(resid + base))[tid];
  const float4 bv = ((const float4*)bias)[tid];
  v.x += bv.x; v.y += bv.y; v.z += bv.z; v.w += bv.w;
#pragma unroll
  for (int s = 0; s < S; ++s) {
    const float4 p = ((const float4*)(part + (size_t)s * 4096 * 1024 + base))[tid];
    v.x += p.x; v.y += p.y; v.z += p.z; v.w += p.w;
  }
  float sm  = v.x + v.y + v.z + v.w;
  float ss = v.x * v.x + v.y * v.y + v.z * v.z + v.w * v.w;
#pragma unroll
  for (int off = 1; off < 64; off <<= 1) {
    sm += __shfl_xor(sm, off);
    ss += __shfl_xor(ss, off);
  }
  __shared__ float red[8];
  if ((tid & 63) == 0) { red[tid >> 6] = sm; red[4 + (tid >> 6)] = ss; }
  __syncthreads();
  sm = red[0] + red[1] + red[2] + red[3];
  ss = red[4] + red[5] + red[6] + red[7];
  const float mu = sm * (1.0f / 1024.0f);
  const float rs = rsqrtf(ss * (1.0f / 1024.0f) - mu * mu + 1e-5f);
  const float4 gg = ((const float4*)g)[tid];
  const float4 bb = ((const float4*)be)[tid];
  float4 y;
  y.x = (v.x - mu) * rs * gg.x + bb.x;
  y.y = (v.y - mu) * rs * gg.y + bb.y;
  y.z = (v.z - mu) * rs * gg.z + bb.z;
  y.w = (v.w - mu) * rs * gg.w + bb.w;
  ((float4*)(outf + base))[tid] = y;
  if (WB) {
    bf4 o4;
    o4.h[0] = __float2bfloat16(y.x);
    o4.h[1] = __float2bfloat16(y.y);
    o4.h[2] = __float2bfloat16(y.z);
    o4.h[3] = __float2bfloat16(y.w);
    *(bf4*)(outb + base + tid * 4) = o4;
  }
}

// ---------------------------------------------------------------------------
extern "C" void kernel_launch(void* const* d_in, const int* in_sizes, int n_in,
                              void* d_out, int out_size, void* d_ws, size_t ws_size,
                              hipStream_t stream) {
  const float* x    = (const float*)d_in[0];
  const float* Wqkv = (const float*)d_in[1];
  const float* bqkv = (const float*)d_in[2];
  const float* Wo   = (const float*)d_in[3];
  const float* bo   = (const float*)d_in[4];
  const float* W1   = (const float*)d_in[5];
  const float* b1   = (const float*)d_in[6];
  const float* W2   = (const float*)d_in[7];
  const float* b2   = (const float*)d_in[8];
  const float* g1   = (const float*)d_in[9];
  const float* be1  = (const float*)d_in[10];
  const float* g2   = (const float*)d_in[11];
  const float* be2  = (const float*)d_in[12];

  char* ws = (char*)d_ws;
  size_t off = 0;
  auto alloc = [&](size_t bytes) -> void* {
    void* p = ws + off;
    off += (bytes + 255) & ~(size_t)255;
    return p;
  };
  __hip_bfloat16* wbuf = (__hip_bfloat16*)alloc(8u << 20);       // reused weight buf
  __hip_bfloat16* xb   = (__hip_bfloat16*)alloc(8388608);        // x bf16
  __hip_bfloat16* qkvb = (__hip_bfloat16*)alloc(25165824);       // [4096,3072]
  __hip_bfloat16* vtb  = (__hip_bfloat16*)alloc(8388608);        // V transposed
  __hip_bfloat16* ctxb = (__hip_bfloat16*)alloc(8388608);        // attn context
  float*          part = (float*)alloc(4u * 16777216);           // split-K partials (<=4)
  float*          x1f  = (float*)alloc(16777216);                // LN1 out f32
  __hip_bfloat16* x1b  = (__hip_bfloat16*)alloc(8388608);        // LN1 out bf16
  __hip_bfloat16* hb   = (__hip_bfloat16*)alloc(33554432);       // gelu(ffn1) [4096,4096]
  (void)ws_size; (void)in_sizes; (void)n_in; (void)out_size;

  // 1. casts + QKV projection
  cast_kernel<<<4096, 256, 0, stream>>>(x, xb);
  cast_kernel<<<3072, 256, 0, stream>>>(Wqkv, wbuf);
  gemm_bt<0><<<dim3(24, 32), 256, 0, stream>>>(xb, wbuf, bqkv, qkvb, 4096, 3072, 1024);
  // 2. attention
  transpose_v_kernel<<<dim3(16, 64), 256, 0, stream>>>(qkvb, vtb);
  attn_kernel<<<1024, 256, 0, stream>>>(qkvb, vtb, ctxb);
  // 3. output projection (split-K=2) + fused reduce+resid+LN1
  cast_kernel<<<1024, 256, 0, stream>>>(Wo, wbuf);
  gemm_bt_splitk<<<dim3(8, 32, 2), 256, 0, stream>>>(ctxb, wbuf, part, 4096, 1024, 1024, 512);
  ln_sum_kernel<2, 1><<<4096, 256, 0, stream>>>(part, x, bo, g1, be1, x1f, x1b);
  // 4. FFN
  cast_kernel<<<4096, 256, 0, stream>>>(W1, wbuf);
  gemm_bt<1><<<dim3(32, 32), 256, 0, stream>>>(x1b, wbuf, b1, hb, 4096, 4096, 1024);
  cast_kernel<<<4096, 256, 0, stream>>>(W2, wbuf);
  gemm_bt_splitk<<<dim3(8, 32, 4), 256, 0, stream>>>(hb, wbuf, part, 4096, 1024, 4096, 1024);
  ln_sum_kernel<4, 0><<<4096, 256, 0, stream>>>(part, x1f, b2, g2, be2, (float*)d_out, nullptr);
}

// Round 5
// 386.047 us; speedup vs baseline: 1.0915x; 1.0319x over previous
//
#include <hip/hip_runtime.h>
#include <hip/hip_bf16.h>

typedef __attribute__((ext_vector_type(4))) float floatx4;
typedef __attribute__((ext_vector_type(8))) short shortx8;

struct bf4 { __hip_bfloat16 h[4]; };  // 8-byte pack for bf16 stores
union U8 { shortx8 v; __hip_bfloat16 h[8]; };

__device__ __forceinline__ void async_copy16(const __hip_bfloat16* g, __hip_bfloat16* l) {
  __builtin_amdgcn_global_load_lds((__attribute__((address_space(1))) void*)g,
                                   (__attribute__((address_space(3))) void*)l,
                                   16, 0, 0);
}

// ---------------------------------------------------------------------------
// fp32 -> bf16 cast, 4 elems/thread
// ---------------------------------------------------------------------------
__global__ __launch_bounds__(256) void cast_kernel(const float* __restrict__ in,
                                                   __hip_bfloat16* __restrict__ out) {
  const int i = blockIdx.x * 256 + threadIdx.x;
  const float4 v = ((const float4*)in)[i];
  bf4 o4;
  o4.h[0] = __float2bfloat16(v.x);
  o4.h[1] = __float2bfloat16(v.y);
  o4.h[2] = __float2bfloat16(v.z);
  o4.h[3] = __float2bfloat16(v.w);
  *(bf4*)(out + (size_t)i * 4) = o4;
}

// LDS k-chunk swizzle (both GEMMs):
//   global_load_lds forces LDS layout = contiguous in lane order (no padding),
//   and row stride 64B = 16 banks makes the fragment ds_read_b128 8-way
//   bank-conflicted (measured 4.19M conflict cycles/dispatch). Rotating the
//   16B k-chunk by (row>>1) mod 4 puts the 16-lane read set at exactly 2
//   lanes per bank group -> 2-way, which is free (m136).
//   stage:  thread tid puts logical chunk ((tid&3)-(tid>>3))&3 at phys tid&3
//   read:   lane (fr,fq) reads phys chunk (fq + (fr>>1)) & 3

// ---------------------------------------------------------------------------
// GEMM C[M,N] = A[M,K] * B[N,K]^T  (bf16 in, fp32 acc), 128x128 tile
// EPI: 0 = +bias -> bf16 out; 1 = +bias, gelu(tanh form) -> bf16 out
// ---------------------------------------------------------------------------
template<int EPI>
__global__ __launch_bounds__(256) void gemm_bt(
    const __hip_bfloat16* __restrict__ A,   // [M,K]
    const __hip_bfloat16* __restrict__ B,   // [N,K]
    const float* __restrict__ bias,         // [N]
    __hip_bfloat16* __restrict__ outb,
    int M, int N, int K)
{
  __shared__ __align__(16) __hip_bfloat16 As[128 * 32];
  __shared__ __align__(16) __hip_bfloat16 Bs[128 * 32];
  const int tid  = threadIdx.x;
  const int lane = tid & 63;
  const int wave = tid >> 6;
  const int wr = wave >> 1, wc = wave & 1;
  const long bm = (long)blockIdx.y * 128, bn = (long)blockIdx.x * 128;

  const int srow = tid >> 2;
  const int scol = ((((tid & 3) - (tid >> 3)) & 3) << 3);   // swizzled k-chunk
  const __hip_bfloat16* Ag0 = A + (bm + srow) * (long)K + scol;
  const __hip_bfloat16* Bg0 = B + (bn + srow) * (long)K + scol;
  const long rstride = 64l * K;
  __hip_bfloat16* As0 = &As[tid * 8];
  __hip_bfloat16* Bs0 = &Bs[tid * 8];

  const int fr = lane & 15;
  const int fq = lane >> 4;
  const int sw = (((fq + ((fr >> 1) & 3)) & 3) << 3);       // phys chunk to read

  const floatx4 zero = {0.f, 0.f, 0.f, 0.f};
  floatx4 acc[4][4];
#pragma unroll
  for (int mi = 0; mi < 4; ++mi)
#pragma unroll
    for (int ni = 0; ni < 4; ++ni) acc[mi][ni] = zero;

  for (int k0 = 0; k0 < K; k0 += 32) {
    async_copy16(Ag0 + k0,           As0);
    async_copy16(Ag0 + k0 + rstride, As0 + 64 * 32);
    async_copy16(Bg0 + k0,           Bs0);
    async_copy16(Bg0 + k0 + rstride, Bs0 + 64 * 32);
    __syncthreads();
    shortx8 afr[4], bfr[4];
#pragma unroll
    for (int i = 0; i < 4; ++i) {
      afr[i] = *(const shortx8*)&As[(wr * 64 + i * 16 + fr) * 32 + sw];
      bfr[i] = *(const shortx8*)&Bs[(wc * 64 + i * 16 + fr) * 32 + sw];
    }
#pragma unroll
    for (int mi = 0; mi < 4; ++mi)
#pragma unroll
      for (int ni = 0; ni < 4; ++ni)
        acc[mi][ni] = __builtin_amdgcn_mfma_f32_16x16x32_bf16(afr[mi], bfr[ni], acc[mi][ni], 0, 0, 0);
    __syncthreads();
  }

  // epilogue: C/D layout col = lane&15, row = (lane>>4)*4 + reg
#pragma unroll
  for (int mi = 0; mi < 4; ++mi) {
#pragma unroll
    for (int ni = 0; ni < 4; ++ni) {
      const long col = bn + wc * 64 + ni * 16 + fr;
      const float bv = bias[col];
#pragma unroll
      for (int r = 0; r < 4; ++r) {
        const long row = bm + wr * 64 + mi * 16 + fq * 4 + r;
        float v = acc[mi][ni][r] + bv;
        if (EPI == 1) {
          // gelu, tanh form (max err vs exact ~1e-3, branchless, 1 transcendental)
          const float u = v + 0.044715f * v * v * v;
          v = v / (1.0f + __expf(-1.5957691216057308f * u));
        }
        outb[(size_t)row * N + col] = __float2bfloat16(v);
      }
    }
  }
}

// ---------------------------------------------------------------------------
// Split-K GEMM: each z-slice computes a raw fp32 partial over K/gridDim.z.
// Partials land at part + z*M*N; reduction fused into ln_sum_kernel.
// ---------------------------------------------------------------------------
__global__ __launch_bounds__(256) void gemm_bt_splitk(
    const __hip_bfloat16* __restrict__ A,   // [M,K]
    const __hip_bfloat16* __restrict__ B,   // [N,K]
    float* __restrict__ part,               // [splits, M, N]
    int M, int N, int K, int Klen)
{
  __shared__ __align__(16) __hip_bfloat16 As[128 * 32];
  __shared__ __align__(16) __hip_bfloat16 Bs[128 * 32];
  const int tid  = threadIdx.x;
  const int lane = tid & 63;
  const int wave = tid >> 6;
  const int wr = wave >> 1, wc = wave & 1;
  const long bm = (long)blockIdx.y * 128, bn = (long)blockIdx.x * 128;
  const int kstart = blockIdx.z * Klen;

  const int srow = tid >> 2;
  const int scol = ((((tid & 3) - (tid >> 3)) & 3) << 3);   // swizzled k-chunk
  const __hip_bfloat16* Ag0 = A + (bm + srow) * (long)K + kstart + scol;
  const __hip_bfloat16* Bg0 = B + (bn + srow) * (long)K + kstart + scol;
  const long rstride = 64l * K;
  __hip_bfloat16* As0 = &As[tid * 8];
  __hip_bfloat16* Bs0 = &Bs[tid * 8];

  const int fr = lane & 15;
  const int fq = lane >> 4;
  const int sw = (((fq + ((fr >> 1) & 3)) & 3) << 3);

  const floatx4 zero = {0.f, 0.f, 0.f, 0.f};
  floatx4 acc[4][4];
#pragma unroll
  for (int mi = 0; mi < 4; ++mi)
#pragma unroll
    for (int ni = 0; ni < 4; ++ni) acc[mi][ni] = zero;

  for (int k0 = 0; k0 < Klen; k0 += 32) {
    async_copy16(Ag0 + k0,           As0);
    async_copy16(Ag0 + k0 + rstride, As0 + 64 * 32);
    async_copy16(Bg0 + k0,           Bs0);
    async_copy16(Bg0 + k0 + rstride, Bs0 + 64 * 32);
    __syncthreads();
    shortx8 afr[4], bfr[4];
#pragma unroll
    for (int i = 0; i < 4; ++i) {
      afr[i] = *(const shortx8*)&As[(wr * 64 + i * 16 + fr) * 32 + sw];
      bfr[i] = *(const shortx8*)&Bs[(wc * 64 + i * 16 + fr) * 32 + sw];
    }
#pragma unroll
    for (int mi = 0; mi < 4; ++mi)
#pragma unroll
      for (int ni = 0; ni < 4; ++ni)
        acc[mi][ni] = __builtin_amdgcn_mfma_f32_16x16x32_bf16(afr[mi], bfr[ni], acc[mi][ni], 0, 0, 0);
    __syncthreads();
  }

  float* outp = part + (size_t)blockIdx.z * M * N;
#pragma unroll
  for (int mi = 0; mi < 4; ++mi) {
#pragma unroll
    for (int ni = 0; ni < 4; ++ni) {
      const long col = bn + wc * 64 + ni * 16 + fr;
#pragma unroll
      for (int r = 0; r < 4; ++r) {
        const long row = bm + wr * 64 + mi * 16 + fq * 4 + r;
        outp[(size_t)row * N + col] = acc[mi][ni][r];
      }
    }
  }
}

// ---------------------------------------------------------------------------
// V transpose: qkv v-part [token, h*64+d] -> vt[(bh*64+d)*1024 + token]
// ---------------------------------------------------------------------------
__global__ __launch_bounds__(256) void transpose_v_kernel(
    const __hip_bfloat16* __restrict__ qkv, __hip_bfloat16* __restrict__ vt)
{
  const int bh = blockIdx.y;          // 0..63
  const int tt = blockIdx.x;          // 0..15 token tiles of 64
  const int b = bh >> 4, h = bh & 15;
  __shared__ __hip_bfloat16 tile[64][65];
  const int tid = threadIdx.x;
  const int r = tid >> 2;             // 0..63
  const int c = (tid & 3) << 4;       // 0,16,32,48
  const __hip_bfloat16* src = qkv + (size_t)(b * 1024 + tt * 64 + r) * 3072 + 2048 + h * 64 + c;
  U8 u0, u1;
  u0.v = *(const shortx8*)src;
  u1.v = *(const shortx8*)(src + 8);
#pragma unroll
  for (int j = 0; j < 8; ++j) { tile[r][c + j] = u0.h[j]; tile[r][c + 8 + j] = u1.h[j]; }
  __syncthreads();
  U8 w0, w1;
#pragma unroll
  for (int j = 0; j < 8; ++j) { w0.h[j] = tile[c + j][r]; w1.h[j] = tile[c + 8 + j][r]; }
  __hip_bfloat16* dst = vt + ((size_t)bh * 64 + r) * 1024 + tt * 64 + c;
  *(shortx8*)dst       = w0.v;
  *(shortx8*)(dst + 8) = w1.v;
}

// ---------------------------------------------------------------------------
// Banded-causal flash attention. One wave per (b,h,q-tile of 16).
// ---------------------------------------------------------------------------
__global__ __launch_bounds__(256) void attn_kernel(
    const __hip_bfloat16* __restrict__ qkv,  // [4096, 3072]
    const __hip_bfloat16* __restrict__ vt,   // [64*64, 1024]
    __hip_bfloat16* __restrict__ ctx)        // [4096, 1024]
{
  const int wave = threadIdx.x >> 6;
  const int lane = threadIdx.x & 63;
  const int gw = blockIdx.x * 4 + wave;   // 0..4095
  const int qt = gw & 63;
  const int bh = gw >> 6;
  const int b = bh >> 4, h = bh & 15;
  const int fr = lane & 15, fq = lane >> 4;
  const int q0 = qt << 4;

  __shared__ __align__(16) __hip_bfloat16 Plds[4][16 * 32];
  __hip_bfloat16* Pw = Plds[wave];

  const __hip_bfloat16* qrow = qkv + (size_t)(b * 1024 + q0 + fr) * 3072 + h * 64;
  const shortx8 aq0 = *(const shortx8*)(qrow + fq * 8);
  const shortx8 aq1 = *(const shortx8*)(qrow + 32 + fq * 8);

  const float SC = 0.125f * 1.44269504088896f;  // scale * log2(e)
  float m_r[4] = {-1e30f, -1e30f, -1e30f, -1e30f};
  float l_r[4] = {0.f, 0.f, 0.f, 0.f};
  const floatx4 zero = {0.f, 0.f, 0.f, 0.f};
  floatx4 o[4];
#pragma unroll
  for (int nd = 0; nd < 4; ++nd) o[nd] = zero;

  const int kt0 = (q0 >= 255) ? ((q0 - 255) >> 5) : 0;  // earliest visible key: q0-255
  const int kt1 = (q0 + 15) >> 5;
  for (int kt = kt0; kt <= kt1; ++kt) {
    const int kbase = kt << 5;
    const __hip_bfloat16* krow0 = qkv + (size_t)(b * 1024 + kbase + fr) * 3072 + 1024 + h * 64;
    const __hip_bfloat16* krow1 = krow0 + 16 * 3072;
    const shortx8 bk00 = *(const shortx8*)(krow0 + fq * 8);
    const shortx8 bk01 = *(const shortx8*)(krow0 + 32 + fq * 8);
    const shortx8 bk10 = *(const shortx8*)(krow1 + fq * 8);
    const shortx8 bk11 = *(const shortx8*)(krow1 + 32 + fq * 8);
    floatx4 s0 = zero, s1 = zero;
    s0 = __builtin_amdgcn_mfma_f32_16x16x32_bf16(aq0, bk00, s0, 0, 0, 0);
    s0 = __builtin_amdgcn_mfma_f32_16x16x32_bf16(aq1, bk01, s0, 0, 0, 0);
    s1 = __builtin_amdgcn_mfma_f32_16x16x32_bf16(aq0, bk10, s1, 0, 0, 0);
    s1 = __builtin_amdgcn_mfma_f32_16x16x32_bf16(aq1, bk11, s1, 0, 0, 0);
#pragma unroll
    for (int r = 0; r < 4; ++r) { s0[r] *= SC; s1[r] *= SC; }
    if (kbase + 31 > q0 || kbase < q0 - 240) {   // wave-uniform (mask bound: query q0+15)
#pragma unroll
      for (int r = 0; r < 4; ++r) {
        const int tq = q0 + fq * 4 + r;
        const int j0 = kbase + fr;
        const int j1 = j0 + 16;
        if (j0 > tq || j0 < tq - 255) s0[r] = -3e38f;
        if (j1 > tq || j1 < tq - 255) s1[r] = -3e38f;
      }
    }
#pragma unroll
    for (int r = 0; r < 4; ++r) {
      float vmax = fmaxf(s0[r], s1[r]);
      vmax = fmaxf(vmax, __shfl_xor(vmax, 1));
      vmax = fmaxf(vmax, __shfl_xor(vmax, 2));
      vmax = fmaxf(vmax, __shfl_xor(vmax, 4));
      vmax = fmaxf(vmax, __shfl_xor(vmax, 8));
      const float mnew = fmaxf(m_r[r], vmax);
      const float alpha = exp2f(m_r[r] - mnew);
      const float p0 = exp2f(s0[r] - mnew);
      const float p1 = exp2f(s1[r] - mnew);
      m_r[r] = mnew;
      float ps = p0 + p1;
      ps += __shfl_xor(ps, 1);
      ps += __shfl_xor(ps, 2);
      ps += __shfl_xor(ps, 4);
      ps += __shfl_xor(ps, 8);
      l_r[r] = l_r[r] * alpha + ps;
      o[0][r] *= alpha; o[1][r] *= alpha; o[2][r] *= alpha; o[3][r] *= alpha;
      Pw[(fq * 4 + r) * 32 + fr]      = __float2bfloat16(p0);
      Pw[(fq * 4 + r) * 32 + 16 + fr] = __float2bfloat16(p1);
    }
    asm volatile("s_waitcnt lgkmcnt(0)" ::: "memory");
    const shortx8 ap = *(const shortx8*)&Pw[fr * 32 + fq * 8];
#pragma unroll
    for (int nd = 0; nd < 4; ++nd) {
      const shortx8 bv = *(const shortx8*)&vt[((size_t)bh * 64 + nd * 16 + fr) * 1024 + kbase + fq * 8];
      o[nd] = __builtin_amdgcn_mfma_f32_16x16x32_bf16(ap, bv, o[nd], 0, 0, 0);
    }
    asm volatile("s_waitcnt lgkmcnt(0)" ::: "memory");
  }
#pragma unroll
  for (int nd = 0; nd < 4; ++nd)
#pragma unroll
    for (int r = 0; r < 4; ++r)
      ctx[(size_t)(b * 1024 + q0 + fq * 4 + r) * 1024 + h * 64 + nd * 16 + fr] =
          __float2bfloat16(o[nd][r] / l_r[r]);
}

// ---------------------------------------------------------------------------
// Fused split-K reduce + bias + residual + LayerNorm. One block per row.
// ---------------------------------------------------------------------------
template<int S, int WB>
__global__ __launch_bounds__(256) void ln_sum_kernel(
    const float* __restrict__ part,   // [S, 4096, 1024]
    const float* __restrict__ resid,  // [4096, 1024]
    const float* __restrict__ bias,   // [1024]
    const float* __restrict__ g, const float* __restrict__ be,
    float* __restrict__ outf, __hip_bfloat16* __restrict__ outb)
{
  const int row = blockIdx.x;
  const int tid = threadIdx.x;
  const size_t base = (size_t)row * 1024;
  float4 v = ((const float4*)(resid + base))[tid];
  const float4 bv = ((const float4*)bias)[tid];
  v.x += bv.x; v.y += bv.y; v.z += bv.z; v.w += bv.w;
#pragma unroll
  for (int s = 0; s < S; ++s) {
    const float4 p = ((const float4*)(part + (size_t)s * 4096 * 1024 + base))[tid];
    v.x += p.x; v.y += p.y; v.z += p.z; v.w += p.w;
  }
  float sm  = v.x + v.y + v.z + v.w;
  float ss = v.x * v.x + v.y * v.y + v.z * v.z + v.w * v.w;
#pragma unroll
  for (int off = 1; off < 64; off <<= 1) {
    sm += __shfl_xor(sm, off);
    ss += __shfl_xor(ss, off);
  }
  __shared__ float red[8];
  if ((tid & 63) == 0) { red[tid >> 6] = sm; red[4 + (tid >> 6)] = ss; }
  __syncthreads();
  sm = red[0] + red[1] + red[2] + red[3];
  ss = red[4] + red[5] + red[6] + red[7];
  const float mu = sm * (1.0f / 1024.0f);
  const float rs = rsqrtf(ss * (1.0f / 1024.0f) - mu * mu + 1e-5f);
  const float4 gg = ((const float4*)g)[tid];
  const float4 bb = ((const float4*)be)[tid];
  float4 y;
  y.x = (v.x - mu) * rs * gg.x + bb.x;
  y.y = (v.y - mu) * rs * gg.y + bb.y;
  y.z = (v.z - mu) * rs * gg.z + bb.z;
  y.w = (v.w - mu) * rs * gg.w + bb.w;
  ((float4*)(outf + base))[tid] = y;
  if (WB) {
    bf4 o4;
    o4.h[0] = __float2bfloat16(y.x);
    o4.h[1] = __float2bfloat16(y.y);
    o4.h[2] = __float2bfloat16(y.z);
    o4.h[3] = __float2bfloat16(y.w);
    *(bf4*)(outb + base + tid * 4) = o4;
  }
}

// ---------------------------------------------------------------------------
extern "C" void kernel_launch(void* const* d_in, const int* in_sizes, int n_in,
                              void* d_out, int out_size, void* d_ws, size_t ws_size,
                              hipStream_t stream) {
  const float* x    = (const float*)d_in[0];
  const float* Wqkv = (const float*)d_in[1];
  const float* bqkv = (const float*)d_in[2];
  const float* Wo   = (const float*)d_in[3];
  const float* bo   = (const float*)d_in[4];
  const float* W1   = (const float*)d_in[5];
  const float* b1   = (const float*)d_in[6];
  const float* W2   = (const float*)d_in[7];
  const float* b2   = (const float*)d_in[8];
  const float* g1   = (const float*)d_in[9];
  const float* be1  = (const float*)d_in[10];
  const float* g2   = (const float*)d_in[11];
  const float* be2  = (const float*)d_in[12];

  char* ws = (char*)d_ws;
  size_t off = 0;
  auto alloc = [&](size_t bytes) -> void* {
    void* p = ws + off;
    off += (bytes + 255) & ~(size_t)255;
    return p;
  };
  __hip_bfloat16* wbuf = (__hip_bfloat16*)alloc(8u << 20);       // reused weight buf
  __hip_bfloat16* xb   = (__hip_bfloat16*)alloc(8388608);        // x bf16
  __hip_bfloat16* qkvb = (__hip_bfloat16*)alloc(25165824);       // [4096,3072]
  __hip_bfloat16* vtb  = (__hip_bfloat16*)alloc(8388608);        // V transposed
  __hip_bfloat16* ctxb = (__hip_bfloat16*)alloc(8388608);        // attn context
  float*          part = (float*)alloc(4u * 16777216);           // split-K partials (<=4)
  float*          x1f  = (float*)alloc(16777216);                // LN1 out f32
  __hip_bfloat16* x1b  = (__hip_bfloat16*)alloc(8388608);        // LN1 out bf16
  __hip_bfloat16* hb   = (__hip_bfloat16*)alloc(33554432);       // gelu(ffn1) [4096,4096]
  (void)ws_size; (void)in_sizes; (void)n_in; (void)out_size;

  // 1. casts + QKV projection
  cast_kernel<<<4096, 256, 0, stream>>>(x, xb);
  cast_kernel<<<3072, 256, 0, stream>>>(Wqkv, wbuf);
  gemm_bt<0><<<dim3(24, 32), 256, 0, stream>>>(xb, wbuf, bqkv, qkvb, 4096, 3072, 1024);
  // 2. attention
  transpose_v_kernel<<<dim3(16, 64), 256, 0, stream>>>(qkvb, vtb);
  attn_kernel<<<1024, 256, 0, stream>>>(qkvb, vtb, ctxb);
  // 3. output projection (split-K=2) + fused reduce+resid+LN1
  cast_kernel<<<1024, 256, 0, stream>>>(Wo, wbuf);
  gemm_bt_splitk<<<dim3(8, 32, 2), 256, 0, stream>>>(ctxb, wbuf, part, 4096, 1024, 1024, 512);
  ln_sum_kernel<2, 1><<<4096, 256, 0, stream>>>(part, x, bo, g1, be1, x1f, x1b);
  // 4. FFN
  cast_kernel<<<4096, 256, 0, stream>>>(W1, wbuf);
  gemm_bt<1><<<dim3(32, 32), 256, 0, stream>>>(x1b, wbuf, b1, hb, 4096, 4096, 1024);
  cast_kernel<<<4096, 256, 0, stream>>>(W2, wbuf);
  gemm_bt_splitk<<<dim3(8, 32, 4), 256, 0, stream>>>(hb, wbuf, part, 4096, 1024, 4096, 1024);
  ln_sum_kernel<4, 0><<<4096, 256, 0, stream>>>(part, x1f, b2, g2, be2, (float*)d_out, nullptr);
}

// Round 6
// 369.156 us; speedup vs baseline: 1.1414x; 1.0458x over previous
//
#include <hip/hip_runtime.h>
#include <hip/hip_bf16.h>

typedef __attribute__((ext_vector_type(4))) float floatx4;
typedef __attribute__((ext_vector_type(8))) short shortx8;

struct bf4 { __hip_bfloat16 h[4]; };
union U8 { shortx8 v; __hip_bfloat16 h[8]; };

__device__ __forceinline__ void async_copy16(const __hip_bfloat16* g, __hip_bfloat16* l) {
  __builtin_amdgcn_global_load_lds((__attribute__((address_space(1))) void*)g,
                                   (__attribute__((address_space(3))) void*)l,
                                   16, 0, 0);
}

// ---------------------------------------------------------------------------
// fp32 -> bf16 cast
// ---------------------------------------------------------------------------
__global__ __launch_bounds__(256) void cast_kernel(const float* __restrict__ in,
                                                   __hip_bfloat16* __restrict__ out) {
  const int i = blockIdx.x * 256 + threadIdx.x;
  const float4 v = ((const float4*)in)[i];
  bf4 o4;
  o4.h[0] = __float2bfloat16(v.x);
  o4.h[1] = __float2bfloat16(v.y);
  o4.h[2] = __float2bfloat16(v.z);
  o4.h[3] = __float2bfloat16(v.w);
  *(bf4*)(out + (size_t)i * 4) = o4;
}

// Pipelined K-loop (AITER-style, see round-5 analysis):
//   double LDS buffers; iter k issues iter-k+1's global_load_lds into the
//   other buffer, then waits only vmcnt(4) (its own iter-k loads) before a
//   RAW s_barrier -> the prefetch stays in flight across the barrier and the
//   whole compute phase. __syncthreads would force vmcnt(0) (the m97 ~20%+
//   drain stall). Race-safety: buf[cur^1]'s readers finished before iter
//   k-1's trailing barrier, which precedes iter-k's prefetch issue.
// LDS swizzle (round 4, verified conflicts=0): phys 16B chunk
//   p = (logical + (row>>1)) & 3 on both staging and fragment reads.

#define GEMM_STAGE(buf, koff)                                      \
  async_copy16(Ag0 + (koff),           &As[buf][tid * 8]);         \
  async_copy16(Ag0 + (koff) + rstride, &As[buf][tid * 8 + 2048]);  \
  async_copy16(Bg0 + (koff),           &Bs[buf][tid * 8]);         \
  async_copy16(Bg0 + (koff) + rstride, &Bs[buf][tid * 8 + 2048]);

#define GEMM_KLOOP(NI)                                                        \
  GEMM_STAGE(0, 0)                                                            \
  for (int it = 0; it < (NI); ++it) {                                         \
    const int cur = it & 1;                                                   \
    if (it + 1 < (NI)) {                                                      \
      GEMM_STAGE(cur ^ 1, (it + 1) * 32)                                      \
      asm volatile("s_waitcnt vmcnt(4)" ::: "memory");                        \
    } else {                                                                  \
      asm volatile("s_waitcnt vmcnt(0)" ::: "memory");                        \
    }                                                                         \
    asm volatile("s_barrier" ::: "memory");                                   \
    const __hip_bfloat16* Ac = As[cur];                                       \
    const __hip_bfloat16* Bc = Bs[cur];                                       \
    shortx8 afr[4], bfr[4];                                                   \
    _Pragma("unroll")                                                         \
    for (int i = 0; i < 4; ++i) {                                             \
      afr[i] = *(const shortx8*)&Ac[(wr * 64 + i * 16 + fr) * 32 + sw];       \
      bfr[i] = *(const shortx8*)&Bc[(wc * 64 + i * 16 + fr) * 32 + sw];       \
    }                                                                         \
    _Pragma("unroll")                                                         \
    for (int mi = 0; mi < 4; ++mi)                                            \
      _Pragma("unroll")                                                       \
      for (int ni = 0; ni < 4; ++ni)                                          \
        acc[mi][ni] = __builtin_amdgcn_mfma_f32_16x16x32_bf16(                \
            afr[mi], bfr[ni], acc[mi][ni], 0, 0, 0);                          \
    asm volatile("s_barrier" ::: "memory");                                   \
  }

// ---------------------------------------------------------------------------
// GEMM C[M,N] = A[M,K] * B[N,K]^T  (bf16 in, fp32 acc), 128x128 tile
// EPI: 0 = +bias -> bf16 out; 1 = +bias, gelu(tanh form) -> bf16 out
// ---------------------------------------------------------------------------
template<int EPI>
__global__ __launch_bounds__(256) void gemm_bt(
    const __hip_bfloat16* __restrict__ A,   // [M,K]
    const __hip_bfloat16* __restrict__ B,   // [N,K]
    const float* __restrict__ bias,         // [N]
    __hip_bfloat16* __restrict__ outb,
    int M, int N, int K)
{
  __shared__ __align__(16) __hip_bfloat16 As[2][128 * 32];
  __shared__ __align__(16) __hip_bfloat16 Bs[2][128 * 32];
  const int tid  = threadIdx.x;
  const int lane = tid & 63;
  const int wave = tid >> 6;
  const int wr = wave >> 1, wc = wave & 1;
  const long bm = (long)blockIdx.y * 128, bn = (long)blockIdx.x * 128;

  const int srow = tid >> 2;
  const int scol = ((((tid & 3) - (tid >> 3)) & 3) << 3);   // swizzled k-chunk
  const __hip_bfloat16* Ag0 = A + (bm + srow) * (long)K + scol;
  const __hip_bfloat16* Bg0 = B + (bn + srow) * (long)K + scol;
  const long rstride = 64l * K;

  const int fr = lane & 15;
  const int fq = lane >> 4;
  const int sw = (((fq + ((fr >> 1) & 3)) & 3) << 3);       // phys chunk to read

  const floatx4 zero = {0.f, 0.f, 0.f, 0.f};
  floatx4 acc[4][4];
#pragma unroll
  for (int mi = 0; mi < 4; ++mi)
#pragma unroll
    for (int ni = 0; ni < 4; ++ni) acc[mi][ni] = zero;

  const int NI = K >> 5;
  GEMM_KLOOP(NI)

  // epilogue: C/D layout col = lane&15, row = (lane>>4)*4 + reg
#pragma unroll
  for (int mi = 0; mi < 4; ++mi) {
#pragma unroll
    for (int ni = 0; ni < 4; ++ni) {
      const long col = bn + wc * 64 + ni * 16 + fr;
      const float bv = bias[col];
#pragma unroll
      for (int r = 0; r < 4; ++r) {
        const long row = bm + wr * 64 + mi * 16 + fq * 4 + r;
        float v = acc[mi][ni][r] + bv;
        if (EPI == 1) {
          const float u = v + 0.044715f * v * v * v;
          v = v / (1.0f + __expf(-1.5957691216057308f * u));
        }
        outb[(size_t)row * N + col] = __float2bfloat16(v);
      }
    }
  }
}

// ---------------------------------------------------------------------------
// Split-K GEMM: z-slice computes raw fp32 partial over Klen; reduce in LN.
// ---------------------------------------------------------------------------
__global__ __launch_bounds__(256) void gemm_bt_splitk(
    const __hip_bfloat16* __restrict__ A,   // [M,K]
    const __hip_bfloat16* __restrict__ B,   // [N,K]
    float* __restrict__ part,               // [splits, M, N]
    int M, int N, int K, int Klen)
{
  __shared__ __align__(16) __hip_bfloat16 As[2][128 * 32];
  __shared__ __align__(16) __hip_bfloat16 Bs[2][128 * 32];
  const int tid  = threadIdx.x;
  const int lane = tid & 63;
  const int wave = tid >> 6;
  const int wr = wave >> 1, wc = wave & 1;
  const long bm = (long)blockIdx.y * 128, bn = (long)blockIdx.x * 128;
  const int kstart = blockIdx.z * Klen;

  const int srow = tid >> 2;
  const int scol = ((((tid & 3) - (tid >> 3)) & 3) << 3);
  const __hip_bfloat16* Ag0 = A + (bm + srow) * (long)K + kstart + scol;
  const __hip_bfloat16* Bg0 = B + (bn + srow) * (long)K + kstart + scol;
  const long rstride = 64l * K;

  const int fr = lane & 15;
  const int fq = lane >> 4;
  const int sw = (((fq + ((fr >> 1) & 3)) & 3) << 3);

  const floatx4 zero = {0.f, 0.f, 0.f, 0.f};
  floatx4 acc[4][4];
#pragma unroll
  for (int mi = 0; mi < 4; ++mi)
#pragma unroll
    for (int ni = 0; ni < 4; ++ni) acc[mi][ni] = zero;

  const int NI = Klen >> 5;
  GEMM_KLOOP(NI)

  float* outp = part + (size_t)blockIdx.z * M * N;
#pragma unroll
  for (int mi = 0; mi < 4; ++mi) {
#pragma unroll
    for (int ni = 0; ni < 4; ++ni) {
      const long col = bn + wc * 64 + ni * 16 + fr;
#pragma unroll
      for (int r = 0; r < 4; ++r) {
        const long row = bm + wr * 64 + mi * 16 + fq * 4 + r;
        outp[(size_t)row * N + col] = acc[mi][ni][r];
      }
    }
  }
}

// ---------------------------------------------------------------------------
// V transpose: qkv v-part [token, h*64+d] -> vt[(bh*64+d)*1024 + token]
// ---------------------------------------------------------------------------
__global__ __launch_bounds__(256) void transpose_v_kernel(
    const __hip_bfloat16* __restrict__ qkv, __hip_bfloat16* __restrict__ vt)
{
  const int bh = blockIdx.y;
  const int tt = blockIdx.x;
  const int b = bh >> 4, h = bh & 15;
  __shared__ __hip_bfloat16 tile[64][65];
  const int tid = threadIdx.x;
  const int r = tid >> 2;
  const int c = (tid & 3) << 4;
  const __hip_bfloat16* src = qkv + (size_t)(b * 1024 + tt * 64 + r) * 3072 + 2048 + h * 64 + c;
  U8 u0, u1;
  u0.v = *(const shortx8*)src;
  u1.v = *(const shortx8*)(src + 8);
#pragma unroll
  for (int j = 0; j < 8; ++j) { tile[r][c + j] = u0.h[j]; tile[r][c + 8 + j] = u1.h[j]; }
  __syncthreads();
  U8 w0, w1;
#pragma unroll
  for (int j = 0; j < 8; ++j) { w0.h[j] = tile[c + j][r]; w1.h[j] = tile[c + 8 + j][r]; }
  __hip_bfloat16* dst = vt + ((size_t)bh * 64 + r) * 1024 + tt * 64 + c;
  *(shortx8*)dst       = w0.v;
  *(shortx8*)(dst + 8) = w1.v;
}

// ---------------------------------------------------------------------------
// Banded-causal flash attention. One wave per (b,h,q-tile of 16).
// ---------------------------------------------------------------------------
__global__ __launch_bounds__(256) void attn_kernel(
    const __hip_bfloat16* __restrict__ qkv,
    const __hip_bfloat16* __restrict__ vt,
    __hip_bfloat16* __restrict__ ctx)
{
  const int wave = threadIdx.x >> 6;
  const int lane = threadIdx.x & 63;
  const int gw = blockIdx.x * 4 + wave;
  const int qt = gw & 63;
  const int bh = gw >> 6;
  const int b = bh >> 4, h = bh & 15;
  const int fr = lane & 15, fq = lane >> 4;
  const int q0 = qt << 4;

  __shared__ __align__(16) __hip_bfloat16 Plds[4][16 * 32];
  __hip_bfloat16* Pw = Plds[wave];

  const __hip_bfloat16* qrow = qkv + (size_t)(b * 1024 + q0 + fr) * 3072 + h * 64;
  const shortx8 aq0 = *(const shortx8*)(qrow + fq * 8);
  const shortx8 aq1 = *(const shortx8*)(qrow + 32 + fq * 8);

  const float SC = 0.125f * 1.44269504088896f;
  float m_r[4] = {-1e30f, -1e30f, -1e30f, -1e30f};
  float l_r[4] = {0.f, 0.f, 0.f, 0.f};
  const floatx4 zero = {0.f, 0.f, 0.f, 0.f};
  floatx4 o[4];
#pragma unroll
  for (int nd = 0; nd < 4; ++nd) o[nd] = zero;

  const int kt0 = (q0 >= 255) ? ((q0 - 255) >> 5) : 0;
  const int kt1 = (q0 + 15) >> 5;
  for (int kt = kt0; kt <= kt1; ++kt) {
    const int kbase = kt << 5;
    const __hip_bfloat16* krow0 = qkv + (size_t)(b * 1024 + kbase + fr) * 3072 + 1024 + h * 64;
    const __hip_bfloat16* krow1 = krow0 + 16 * 3072;
    const shortx8 bk00 = *(const shortx8*)(krow0 + fq * 8);
    const shortx8 bk01 = *(const shortx8*)(krow0 + 32 + fq * 8);
    const shortx8 bk10 = *(const shortx8*)(krow1 + fq * 8);
    const shortx8 bk11 = *(const shortx8*)(krow1 + 32 + fq * 8);
    floatx4 s0 = zero, s1 = zero;
    s0 = __builtin_amdgcn_mfma_f32_16x16x32_bf16(aq0, bk00, s0, 0, 0, 0);
    s0 = __builtin_amdgcn_mfma_f32_16x16x32_bf16(aq1, bk01, s0, 0, 0, 0);
    s1 = __builtin_amdgcn_mfma_f32_16x16x32_bf16(aq0, bk10, s1, 0, 0, 0);
    s1 = __builtin_amdgcn_mfma_f32_16x16x32_bf16(aq1, bk11, s1, 0, 0, 0);
#pragma unroll
    for (int r = 0; r < 4; ++r) { s0[r] *= SC; s1[r] *= SC; }
    if (kbase + 31 > q0 || kbase < q0 - 240) {
#pragma unroll
      for (int r = 0; r < 4; ++r) {
        const int tq = q0 + fq * 4 + r;
        const int j0 = kbase + fr;
        const int j1 = j0 + 16;
        if (j0 > tq || j0 < tq - 255) s0[r] = -3e38f;
        if (j1 > tq || j1 < tq - 255) s1[r] = -3e38f;
      }
    }
#pragma unroll
    for (int r = 0; r < 4; ++r) {
      float vmax = fmaxf(s0[r], s1[r]);
      vmax = fmaxf(vmax, __shfl_xor(vmax, 1));
      vmax = fmaxf(vmax, __shfl_xor(vmax, 2));
      vmax = fmaxf(vmax, __shfl_xor(vmax, 4));
      vmax = fmaxf(vmax, __shfl_xor(vmax, 8));
      const float mnew = fmaxf(m_r[r], vmax);
      const float alpha = exp2f(m_r[r] - mnew);
      const float p0 = exp2f(s0[r] - mnew);
      const float p1 = exp2f(s1[r] - mnew);
      m_r[r] = mnew;
      float ps = p0 + p1;
      ps += __shfl_xor(ps, 1);
      ps += __shfl_xor(ps, 2);
      ps += __shfl_xor(ps, 4);
      ps += __shfl_xor(ps, 8);
      l_r[r] = l_r[r] * alpha + ps;
      o[0][r] *= alpha; o[1][r] *= alpha; o[2][r] *= alpha; o[3][r] *= alpha;
      Pw[(fq * 4 + r) * 32 + fr]      = __float2bfloat16(p0);
      Pw[(fq * 4 + r) * 32 + 16 + fr] = __float2bfloat16(p1);
    }
    asm volatile("s_waitcnt lgkmcnt(0)" ::: "memory");
    const shortx8 ap = *(const shortx8*)&Pw[fr * 32 + fq * 8];
#pragma unroll
    for (int nd = 0; nd < 4; ++nd) {
      const shortx8 bv = *(const shortx8*)&vt[((size_t)bh * 64 + nd * 16 + fr) * 1024 + kbase + fq * 8];
      o[nd] = __builtin_amdgcn_mfma_f32_16x16x32_bf16(ap, bv, o[nd], 0, 0, 0);
    }
    asm volatile("s_waitcnt lgkmcnt(0)" ::: "memory");
  }
#pragma unroll
  for (int nd = 0; nd < 4; ++nd)
#pragma unroll
    for (int r = 0; r < 4; ++r)
      ctx[(size_t)(b * 1024 + q0 + fq * 4 + r) * 1024 + h * 64 + nd * 16 + fr] =
          __float2bfloat16(o[nd][r] / l_r[r]);
}

// ---------------------------------------------------------------------------
// Fused split-K reduce + bias + residual + LayerNorm. One block per row.
// ---------------------------------------------------------------------------
template<int S, int WB>
__global__ __launch_bounds__(256) void ln_sum_kernel(
    const float* __restrict__ part,
    const float* __restrict__ resid,
    const float* __restrict__ bias,
    const float* __restrict__ g, const float* __restrict__ be,
    float* __restrict__ outf, __hip_bfloat16* __restrict__ outb)
{
  const int row = blockIdx.x;
  const int tid = threadIdx.x;
  const size_t base = (size_t)row * 1024;
  float4 v = ((const float4*)(resid + base))[tid];
  const float4 bv = ((const float4*)bias)[tid];
  v.x += bv.x; v.y += bv.y; v.z += bv.z; v.w += bv.w;
#pragma unroll
  for (int s = 0; s < S; ++s) {
    const float4 p = ((const float4*)(part + (size_t)s * 4096 * 1024 + base))[tid];
    v.x += p.x; v.y += p.y; v.z += p.z; v.w += p.w;
  }
  float sm  = v.x + v.y + v.z + v.w;
  float ss = v.x * v.x + v.y * v.y + v.z * v.z + v.w * v.w;
#pragma unroll
  for (int off = 1; off < 64; off <<= 1) {
    sm += __shfl_xor(sm, off);
    ss += __shfl_xor(ss, off);
  }
  __shared__ float red[8];
  if ((tid & 63) == 0) { red[tid >> 6] = sm; red[4 + (tid >> 6)] = ss; }
  __syncthreads();
  sm = red[0] + red[1] + red[2] + red[3];
  ss = red[4] + red[5] + red[6] + red[7];
  const float mu = sm * (1.0f / 1024.0f);
  const float rs = rsqrtf(ss * (1.0f / 1024.0f) - mu * mu + 1e-5f);
  const float4 gg = ((const float4*)g)[tid];
  const float4 bb = ((const float4*)be)[tid];
  float4 y;
  y.x = (v.x - mu) * rs * gg.x + bb.x;
  y.y = (v.y - mu) * rs * gg.y + bb.y;
  y.z = (v.z - mu) * rs * gg.z + bb.z;
  y.w = (v.w - mu) * rs * gg.w + bb.w;
  ((float4*)(outf + base))[tid] = y;
  if (WB) {
    bf4 o4;
    o4.h[0] = __float2bfloat16(y.x);
    o4.h[1] = __float2bfloat16(y.y);
    o4.h[2] = __float2bfloat16(y.z);
    o4.h[3] = __float2bfloat16(y.w);
    *(bf4*)(outb + base + tid * 4) = o4;
  }
}

// ---------------------------------------------------------------------------
extern "C" void kernel_launch(void* const* d_in, const int* in_sizes, int n_in,
                              void* d_out, int out_size, void* d_ws, size_t ws_size,
                              hipStream_t stream) {
  const float* x    = (const float*)d_in[0];
  const float* Wqkv = (const float*)d_in[1];
  const float* bqkv = (const float*)d_in[2];
  const float* Wo   = (const float*)d_in[3];
  const float* bo   = (const float*)d_in[4];
  const float* W1   = (const float*)d_in[5];
  const float* b1   = (const float*)d_in[6];
  const float* W2   = (const float*)d_in[7];
  const float* b2   = (const float*)d_in[8];
  const float* g1   = (const float*)d_in[9];
  const float* be1  = (const float*)d_in[10];
  const float* g2   = (const float*)d_in[11];
  const float* be2  = (const float*)d_in[12];

  char* ws = (char*)d_ws;
  size_t off = 0;
  auto alloc = [&](size_t bytes) -> void* {
    void* p = ws + off;
    off += (bytes + 255) & ~(size_t)255;
    return p;
  };
  __hip_bfloat16* wbuf = (__hip_bfloat16*)alloc(8u << 20);
  __hip_bfloat16* xb   = (__hip_bfloat16*)alloc(8388608);
  __hip_bfloat16* qkvb = (__hip_bfloat16*)alloc(25165824);
  __hip_bfloat16* vtb  = (__hip_bfloat16*)alloc(8388608);
  __hip_bfloat16* ctxb = (__hip_bfloat16*)alloc(8388608);
  float*          part = (float*)alloc(4u * 16777216);
  float*          x1f  = (float*)alloc(16777216);
  __hip_bfloat16* x1b  = (__hip_bfloat16*)alloc(8388608);
  __hip_bfloat16* hb   = (__hip_bfloat16*)alloc(33554432);
  (void)ws_size; (void)in_sizes; (void)n_in; (void)out_size;

  // 1. casts + QKV projection
  cast_kernel<<<4096, 256, 0, stream>>>(x, xb);
  cast_kernel<<<3072, 256, 0, stream>>>(Wqkv, wbuf);
  gemm_bt<0><<<dim3(24, 32), 256, 0, stream>>>(xb, wbuf, bqkv, qkvb, 4096, 3072, 1024);
  // 2. attention
  transpose_v_kernel<<<dim3(16, 64), 256, 0, stream>>>(qkvb, vtb);
  attn_kernel<<<1024, 256, 0, stream>>>(qkvb, vtb, ctxb);
  // 3. output projection (split-K=2) + fused reduce+resid+LN1
  cast_kernel<<<1024, 256, 0, stream>>>(Wo, wbuf);
  gemm_bt_splitk<<<dim3(8, 32, 2), 256, 0, stream>>>(ctxb, wbuf, part, 4096, 1024, 1024, 512);
  ln_sum_kernel<2, 1><<<4096, 256, 0, stream>>>(part, x, bo, g1, be1, x1f, x1b);
  // 4. FFN
  cast_kernel<<<4096, 256, 0, stream>>>(W1, wbuf);
  gemm_bt<1><<<dim3(32, 32), 256, 0, stream>>>(x1b, wbuf, b1, hb, 4096, 4096, 1024);
  cast_kernel<<<4096, 256, 0, stream>>>(W2, wbuf);
  gemm_bt_splitk<<<dim3(8, 32, 4), 256, 0, stream>>>(hb, wbuf, part, 4096, 1024, 4096, 1024);
  ln_sum_kernel<4, 0><<<4096, 256, 0, stream>>>(part, x1f, b2, g2, be2, (float*)d_out, nullptr);
}

// Round 7
// 359.295 us; speedup vs baseline: 1.1727x; 1.0274x over previous
//
#include <hip/hip_runtime.h>
#include <hip/hip_bf16.h>

typedef __attribute__((ext_vector_type(4))) float floatx4;
typedef __attribute__((ext_vector_type(8))) short shortx8;

struct bf4 { __hip_bfloat16 h[4]; };
union U8 { shortx8 v; __hip_bfloat16 h[8]; };
union U4 { unsigned long long v; __hip_bfloat16 h[4]; };

__device__ __forceinline__ void async_copy16(const __hip_bfloat16* g, __hip_bfloat16* l) {
  __builtin_amdgcn_global_load_lds((__attribute__((address_space(1))) void*)g,
                                   (__attribute__((address_space(3))) void*)l,
                                   16, 0, 0);
}

// ---------------------------------------------------------------------------
// One-launch fp32 -> bf16 cast over 5 ranges (x, Wqkv, Wo, W1, W2).
// Block counts per range passed as args; each block does 1024 elems.
// ---------------------------------------------------------------------------
__global__ __launch_bounds__(256) void cast_all_kernel(
    const float* __restrict__ s0, __hip_bfloat16* __restrict__ d0, int nb0,
    const float* __restrict__ s1, __hip_bfloat16* __restrict__ d1, int nb1,
    const float* __restrict__ s2, __hip_bfloat16* __restrict__ d2, int nb2,
    const float* __restrict__ s3, __hip_bfloat16* __restrict__ d3, int nb3,
    const float* __restrict__ s4, __hip_bfloat16* __restrict__ d4) {
  int b = blockIdx.x;
  const float* src; __hip_bfloat16* dst;
  if (b < nb0) { src = s0; dst = d0; }
  else { b -= nb0;
    if (b < nb1) { src = s1; dst = d1; }
    else { b -= nb1;
      if (b < nb2) { src = s2; dst = d2; }
      else { b -= nb2;
        if (b < nb3) { src = s3; dst = d3; }
        else { b -= nb3; src = s4; dst = d4; }
      }
    }
  }
  const int i = b * 256 + threadIdx.x;
  const float4 v = ((const float4*)src)[i];
  bf4 o4;
  o4.h[0] = __float2bfloat16(v.x);
  o4.h[1] = __float2bfloat16(v.y);
  o4.h[2] = __float2bfloat16(v.z);
  o4.h[3] = __float2bfloat16(v.w);
  *(bf4*)(dst + (size_t)i * 4) = o4;
}

// XCD swizzle: with flat dispatch id round-robining over 8 XCDs, remap so
// each XCD owns a disjoint 4-M-tile stripe (A rows fetched once per XCD)
// and only the weight matrix streams cross-XCD (L3-shared). Requires
// gridDim.y == 32 (all our GEMMs). Speed-only heuristic (G16-safe).
#define GEMM_SWIZZLE()                                                        \
  const int flat = blockIdx.x + gridDim.x * (blockIdx.y + 32 * blockIdx.z);   \
  const int xcd_ = flat & 7;                                                  \
  int rsw_ = flat >> 3;                                                       \
  const int mt_ = xcd_ * 4 + (rsw_ & 3);                                      \
  rsw_ >>= 2;                                                                 \
  const int nt_ = rsw_ % gridDim.x;                                           \
  const int zt_ = rsw_ / gridDim.x;

// Pipelined K-loop (round 5, verified): double LDS buffer, prefetch next
// iter then s_waitcnt vmcnt(4) + raw s_barrier -> prefetch stays in flight
// across the barrier. LDS chunk swizzle (round 4, verified conflicts=0).
#define GEMM_STAGE(buf, koff)                                      \
  async_copy16(Ag0 + (koff),           &As[buf][tid * 8]);         \
  async_copy16(Ag0 + (koff) + rstride, &As[buf][tid * 8 + 2048]);  \
  async_copy16(Bg0 + (koff),           &Bs[buf][tid * 8]);         \
  async_copy16(Bg0 + (koff) + rstride, &Bs[buf][tid * 8 + 2048]);

#define GEMM_KLOOP(NI)                                                        \
  GEMM_STAGE(0, 0)                                                            \
  for (int it = 0; it < (NI); ++it) {                                         \
    const int cur = it & 1;                                                   \
    if (it + 1 < (NI)) {                                                      \
      GEMM_STAGE(cur ^ 1, (it + 1) * 32)                                      \
      asm volatile("s_waitcnt vmcnt(4)" ::: "memory");                        \
    } else {                                                                  \
      asm volatile("s_waitcnt vmcnt(0)" ::: "memory");                        \
    }                                                                         \
    asm volatile("s_barrier" ::: "memory");                                   \
    const __hip_bfloat16* Ac = As[cur];                                       \
    const __hip_bfloat16* Bc = Bs[cur];                                       \
    shortx8 afr[4], bfr[4];                                                   \
    _Pragma("unroll")                                                         \
    for (int i = 0; i < 4; ++i) {                                             \
      afr[i] = *(const shortx8*)&Ac[(wr * 64 + i * 16 + fr) * 32 + sw];       \
      bfr[i] = *(const shortx8*)&Bc[(wc * 64 + i * 16 + fr) * 32 + sw];       \
    }                                                                         \
    _Pragma("unroll")                                                         \
    for (int mi = 0; mi < 4; ++mi)                                            \
      _Pragma("unroll")                                                       \
      for (int ni = 0; ni < 4; ++ni)                                          \
        acc[mi][ni] = __builtin_amdgcn_mfma_f32_16x16x32_bf16(                \
            afr[mi], bfr[ni], acc[mi][ni], 0, 0, 0);                          \
    asm volatile("s_barrier" ::: "memory");                                   \
  }

// ---------------------------------------------------------------------------
// GEMM C[M,N] = A[M,K] * B[N,K]^T  (bf16 in, fp32 acc), 128x128 tile
// EPI: 0 = +bias -> bf16 out; 1 = +bias, gelu(tanh form) -> bf16 out
// ---------------------------------------------------------------------------
template<int EPI>
__global__ __launch_bounds__(256) void gemm_bt(
    const __hip_bfloat16* __restrict__ A,   // [M,K]
    const __hip_bfloat16* __restrict__ B,   // [N,K]
    const float* __restrict__ bias,         // [N]
    __hip_bfloat16* __restrict__ outb,
    int M, int N, int K)
{
  __shared__ __align__(16) __hip_bfloat16 As[2][128 * 32];
  __shared__ __align__(16) __hip_bfloat16 Bs[2][128 * 32];
  const int tid  = threadIdx.x;
  const int lane = tid & 63;
  const int wave = tid >> 6;
  const int wr = wave >> 1, wc = wave & 1;
  GEMM_SWIZZLE()
  const long bm = (long)mt_ * 128, bn = (long)nt_ * 128;
  (void)zt_;

  const int srow = tid >> 2;
  const int scol = ((((tid & 3) - (tid >> 3)) & 3) << 3);   // swizzled k-chunk
  const __hip_bfloat16* Ag0 = A + (bm + srow) * (long)K + scol;
  const __hip_bfloat16* Bg0 = B + (bn + srow) * (long)K + scol;
  const long rstride = 64l * K;

  const int fr = lane & 15;
  const int fq = lane >> 4;
  const int sw = (((fq + ((fr >> 1) & 3)) & 3) << 3);       // phys chunk to read

  const floatx4 zero = {0.f, 0.f, 0.f, 0.f};
  floatx4 acc[4][4];
#pragma unroll
  for (int mi = 0; mi < 4; ++mi)
#pragma unroll
    for (int ni = 0; ni < 4; ++ni) acc[mi][ni] = zero;

  const int NI = K >> 5;
  GEMM_KLOOP(NI)

  // epilogue: C/D layout col = lane&15, row = (lane>>4)*4 + reg
#pragma unroll
  for (int mi = 0; mi < 4; ++mi) {
#pragma unroll
    for (int ni = 0; ni < 4; ++ni) {
      const long col = bn + wc * 64 + ni * 16 + fr;
      const float bv = bias[col];
#pragma unroll
      for (int r = 0; r < 4; ++r) {
        const long row = bm + wr * 64 + mi * 16 + fq * 4 + r;
        float v = acc[mi][ni][r] + bv;
        if (EPI == 1) {
          const float u = v + 0.044715f * v * v * v;
          v = v / (1.0f + __expf(-1.5957691216057308f * u));
        }
        outb[(size_t)row * N + col] = __float2bfloat16(v);
      }
    }
  }
}

// ---------------------------------------------------------------------------
// Split-K GEMM: z-slice computes a raw partial over Klen -> bf16 partials
// (halves the partial HBM traffic; reduce fused into ln_sum_kernel).
// ---------------------------------------------------------------------------
__global__ __launch_bounds__(256) void gemm_bt_splitk(
    const __hip_bfloat16* __restrict__ A,   // [M,K]
    const __hip_bfloat16* __restrict__ B,   // [N,K]
    __hip_bfloat16* __restrict__ part,      // [splits, M, N] bf16
    int M, int N, int K, int Klen)
{
  __shared__ __align__(16) __hip_bfloat16 As[2][128 * 32];
  __shared__ __align__(16) __hip_bfloat16 Bs[2][128 * 32];
  const int tid  = threadIdx.x;
  const int lane = tid & 63;
  const int wave = tid >> 6;
  const int wr = wave >> 1, wc = wave & 1;
  GEMM_SWIZZLE()
  const long bm = (long)mt_ * 128, bn = (long)nt_ * 128;
  const int kstart = zt_ * Klen;

  const int srow = tid >> 2;
  const int scol = ((((tid & 3) - (tid >> 3)) & 3) << 3);
  const __hip_bfloat16* Ag0 = A + (bm + srow) * (long)K + kstart + scol;
  const __hip_bfloat16* Bg0 = B + (bn + srow) * (long)K + kstart + scol;
  const long rstride = 64l * K;

  const int fr = lane & 15;
  const int fq = lane >> 4;
  const int sw = (((fq + ((fr >> 1) & 3)) & 3) << 3);

  const floatx4 zero = {0.f, 0.f, 0.f, 0.f};
  floatx4 acc[4][4];
#pragma unroll
  for (int mi = 0; mi < 4; ++mi)
#pragma unroll
    for (int ni = 0; ni < 4; ++ni) acc[mi][ni] = zero;

  const int NI = Klen >> 5;
  GEMM_KLOOP(NI)

  __hip_bfloat16* outp = part + (size_t)zt_ * M * N;
#pragma unroll
  for (int mi = 0; mi < 4; ++mi) {
#pragma unroll
    for (int ni = 0; ni < 4; ++ni) {
      const long col = bn + wc * 64 + ni * 16 + fr;
#pragma unroll
      for (int r = 0; r < 4; ++r) {
        const long row = bm + wr * 64 + mi * 16 + fq * 4 + r;
        outp[(size_t)row * N + col] = __float2bfloat16(acc[mi][ni][r]);
      }
    }
  }
}

// ---------------------------------------------------------------------------
// V transpose: qkv v-part [token, h*64+d] -> vt[(bh*64+d)*1024 + token]
// ---------------------------------------------------------------------------
__global__ __launch_bounds__(256) void transpose_v_kernel(
    const __hip_bfloat16* __restrict__ qkv, __hip_bfloat16* __restrict__ vt)
{
  const int bh = blockIdx.y;
  const int tt = blockIdx.x;
  const int b = bh >> 4, h = bh & 15;
  __shared__ __hip_bfloat16 tile[64][65];
  const int tid = threadIdx.x;
  const int r = tid >> 2;
  const int c = (tid & 3) << 4;
  const __hip_bfloat16* src = qkv + (size_t)(b * 1024 + tt * 64 + r) * 3072 + 2048 + h * 64 + c;
  U8 u0, u1;
  u0.v = *(const shortx8*)src;
  u1.v = *(const shortx8*)(src + 8);
#pragma unroll
  for (int j = 0; j < 8; ++j) { tile[r][c + j] = u0.h[j]; tile[r][c + 8 + j] = u1.h[j]; }
  __syncthreads();
  U8 w0, w1;
#pragma unroll
  for (int j = 0; j < 8; ++j) { w0.h[j] = tile[c + j][r]; w1.h[j] = tile[c + 8 + j][r]; }
  __hip_bfloat16* dst = vt + ((size_t)bh * 64 + r) * 1024 + tt * 64 + c;
  *(shortx8*)dst       = w0.v;
  *(shortx8*)(dst + 8) = w1.v;
}

// ---------------------------------------------------------------------------
// Banded-causal flash attention. One wave per (b,h,q-tile of 16).
// ---------------------------------------------------------------------------
__global__ __launch_bounds__(256) void attn_kernel(
    const __hip_bfloat16* __restrict__ qkv,
    const __hip_bfloat16* __restrict__ vt,
    __hip_bfloat16* __restrict__ ctx)
{
  const int wave = threadIdx.x >> 6;
  const int lane = threadIdx.x & 63;
  const int gw = blockIdx.x * 4 + wave;
  const int qt = gw & 63;
  const int bh = gw >> 6;
  const int b = bh >> 4, h = bh & 15;
  const int fr = lane & 15, fq = lane >> 4;
  const int q0 = qt << 4;

  __shared__ __align__(16) __hip_bfloat16 Plds[4][16 * 32];
  __hip_bfloat16* Pw = Plds[wave];

  const __hip_bfloat16* qrow = qkv + (size_t)(b * 1024 + q0 + fr) * 3072 + h * 64;
  const shortx8 aq0 = *(const shortx8*)(qrow + fq * 8);
  const shortx8 aq1 = *(const shortx8*)(qrow + 32 + fq * 8);

  const float SC = 0.125f * 1.44269504088896f;
  float m_r[4] = {-1e30f, -1e30f, -1e30f, -1e30f};
  float l_r[4] = {0.f, 0.f, 0.f, 0.f};
  const floatx4 zero = {0.f, 0.f, 0.f, 0.f};
  floatx4 o[4];
#pragma unroll
  for (int nd = 0; nd < 4; ++nd) o[nd] = zero;

  const int kt0 = (q0 >= 255) ? ((q0 - 255) >> 5) : 0;
  const int kt1 = (q0 + 15) >> 5;
  for (int kt = kt0; kt <= kt1; ++kt) {
    const int kbase = kt << 5;
    const __hip_bfloat16* krow0 = qkv + (size_t)(b * 1024 + kbase + fr) * 3072 + 1024 + h * 64;
    const __hip_bfloat16* krow1 = krow0 + 16 * 3072;
    const shortx8 bk00 = *(const shortx8*)(krow0 + fq * 8);
    const shortx8 bk01 = *(const shortx8*)(krow0 + 32 + fq * 8);
    const shortx8 bk10 = *(const shortx8*)(krow1 + fq * 8);
    const shortx8 bk11 = *(const shortx8*)(krow1 + 32 + fq * 8);
    floatx4 s0 = zero, s1 = zero;
    s0 = __builtin_amdgcn_mfma_f32_16x16x32_bf16(aq0, bk00, s0, 0, 0, 0);
    s0 = __builtin_amdgcn_mfma_f32_16x16x32_bf16(aq1, bk01, s0, 0, 0, 0);
    s1 = __builtin_amdgcn_mfma_f32_16x16x32_bf16(aq0, bk10, s1, 0, 0, 0);
    s1 = __builtin_amdgcn_mfma_f32_16x16x32_bf16(aq1, bk11, s1, 0, 0, 0);
#pragma unroll
    for (int r = 0; r < 4; ++r) { s0[r] *= SC; s1[r] *= SC; }
    if (kbase + 31 > q0 || kbase < q0 - 240) {
#pragma unroll
      for (int r = 0; r < 4; ++r) {
        const int tq = q0 + fq * 4 + r;
        const int j0 = kbase + fr;
        const int j1 = j0 + 16;
        if (j0 > tq || j0 < tq - 255) s0[r] = -3e38f;
        if (j1 > tq || j1 < tq - 255) s1[r] = -3e38f;
      }
    }
#pragma unroll
    for (int r = 0; r < 4; ++r) {
      float vmax = fmaxf(s0[r], s1[r]);
      vmax = fmaxf(vmax, __shfl_xor(vmax, 1));
      vmax = fmaxf(vmax, __shfl_xor(vmax, 2));
      vmax = fmaxf(vmax, __shfl_xor(vmax, 4));
      vmax = fmaxf(vmax, __shfl_xor(vmax, 8));
      const float mnew = fmaxf(m_r[r], vmax);
      const float alpha = exp2f(m_r[r] - mnew);
      const float p0 = exp2f(s0[r] - mnew);
      const float p1 = exp2f(s1[r] - mnew);
      m_r[r] = mnew;
      float ps = p0 + p1;
      ps += __shfl_xor(ps, 1);
      ps += __shfl_xor(ps, 2);
      ps += __shfl_xor(ps, 4);
      ps += __shfl_xor(ps, 8);
      l_r[r] = l_r[r] * alpha + ps;
      o[0][r] *= alpha; o[1][r] *= alpha; o[2][r] *= alpha; o[3][r] *= alpha;
      Pw[(fq * 4 + r) * 32 + fr]      = __float2bfloat16(p0);
      Pw[(fq * 4 + r) * 32 + 16 + fr] = __float2bfloat16(p1);
    }
    asm volatile("s_waitcnt lgkmcnt(0)" ::: "memory");
    const shortx8 ap = *(const shortx8*)&Pw[fr * 32 + fq * 8];
#pragma unroll
    for (int nd = 0; nd < 4; ++nd) {
      const shortx8 bv = *(const shortx8*)&vt[((size_t)bh * 64 + nd * 16 + fr) * 1024 + kbase + fq * 8];
      o[nd] = __builtin_amdgcn_mfma_f32_16x16x32_bf16(ap, bv, o[nd], 0, 0, 0);
    }
    asm volatile("s_waitcnt lgkmcnt(0)" ::: "memory");
  }
#pragma unroll
  for (int nd = 0; nd < 4; ++nd)
#pragma unroll
    for (int r = 0; r < 4; ++r)
      ctx[(size_t)(b * 1024 + q0 + fq * 4 + r) * 1024 + h * 64 + nd * 16 + fr] =
          __float2bfloat16(o[nd][r] / l_r[r]);
}

// ---------------------------------------------------------------------------
// Fused split-K reduce (bf16 partials) + bias + residual + LayerNorm.
// ---------------------------------------------------------------------------
template<int S, int WB>
__global__ __launch_bounds__(256) void ln_sum_kernel(
    const __hip_bfloat16* __restrict__ part,  // [S, 4096, 1024] bf16
    const float* __restrict__ resid,          // [4096, 1024]
    const float* __restrict__ bias,           // [1024]
    const float* __restrict__ g, const float* __restrict__ be,
    float* __restrict__ outf, __hip_bfloat16* __restrict__ outb)
{
  const int row = blockIdx.x;
  const int tid = threadIdx.x;
  const size_t base = (size_t)row * 1024;
  float4 v = ((const float4*)(resid + base))[tid];
  const float4 bv = ((const float4*)bias)[tid];
  v.x += bv.x; v.y += bv.y; v.z += bv.z; v.w += bv.w;
#pragma unroll
  for (int s = 0; s < S; ++s) {
    U4 p;
    p.v = *(const unsigned long long*)&part[(size_t)s * 4096 * 1024 + base + tid * 4];
    v.x += __bfloat162float(p.h[0]);
    v.y += __bfloat162float(p.h[1]);
    v.z += __bfloat162float(p.h[2]);
    v.w += __bfloat162float(p.h[3]);
  }
  float sm = v.x + v.y + v.z + v.w;
  float ss = v.x * v.x + v.y * v.y + v.z * v.z + v.w * v.w;
#pragma unroll
  for (int off = 1; off < 64; off <<= 1) {
    sm += __shfl_xor(sm, off);
    ss += __shfl_xor(ss, off);
  }
  __shared__ float red[8];
  if ((tid & 63) == 0) { red[tid >> 6] = sm; red[4 + (tid >> 6)] = ss; }
  __syncthreads();
  sm = red[0] + red[1] + red[2] + red[3];
  ss = red[4] + red[5] + red[6] + red[7];
  const float mu = sm * (1.0f / 1024.0f);
  const float rs = rsqrtf(ss * (1.0f / 1024.0f) - mu * mu + 1e-5f);
  const float4 gg = ((const float4*)g)[tid];
  const float4 bb = ((const float4*)be)[tid];
  float4 y;
  y.x = (v.x - mu) * rs * gg.x + bb.x;
  y.y = (v.y - mu) * rs * gg.y + bb.y;
  y.z = (v.z - mu) * rs * gg.z + bb.z;
  y.w = (v.w - mu) * rs * gg.w + bb.w;
  ((float4*)(outf + base))[tid] = y;
  if (WB) {
    bf4 o4;
    o4.h[0] = __float2bfloat16(y.x);
    o4.h[1] = __float2bfloat16(y.y);
    o4.h[2] = __float2bfloat16(y.z);
    o4.h[3] = __float2bfloat16(y.w);
    *(bf4*)(outb + base + tid * 4) = o4;
  }
}

// ---------------------------------------------------------------------------
extern "C" void kernel_launch(void* const* d_in, const int* in_sizes, int n_in,
                              void* d_out, int out_size, void* d_ws, size_t ws_size,
                              hipStream_t stream) {
  const float* x    = (const float*)d_in[0];
  const float* Wqkv = (const float*)d_in[1];
  const float* bqkv = (const float*)d_in[2];
  const float* Wo   = (const float*)d_in[3];
  const float* bo   = (const float*)d_in[4];
  const float* W1   = (const float*)d_in[5];
  const float* b1   = (const float*)d_in[6];
  const float* W2   = (const float*)d_in[7];
  const float* b2   = (const float*)d_in[8];
  const float* g1   = (const float*)d_in[9];
  const float* be1  = (const float*)d_in[10];
  const float* g2   = (const float*)d_in[11];
  const float* be2  = (const float*)d_in[12];

  char* ws = (char*)d_ws;
  size_t off = 0;
  auto alloc = [&](size_t bytes) -> void* {
    void* p = ws + off;
    off += (bytes + 255) & ~(size_t)255;
    return p;
  };
  __hip_bfloat16* wqkvb = (__hip_bfloat16*)alloc(6291456);       // Wqkv bf16
  __hip_bfloat16* wob   = (__hip_bfloat16*)alloc(2097152);       // Wo bf16
  __hip_bfloat16* w1b   = (__hip_bfloat16*)alloc(8388608);       // W1 bf16
  __hip_bfloat16* w2b   = (__hip_bfloat16*)alloc(8388608);       // W2 bf16
  __hip_bfloat16* xb    = (__hip_bfloat16*)alloc(8388608);       // x bf16
  __hip_bfloat16* qkvb  = (__hip_bfloat16*)alloc(25165824);      // [4096,3072]
  __hip_bfloat16* vtb   = (__hip_bfloat16*)alloc(8388608);       // V transposed
  __hip_bfloat16* ctxb  = (__hip_bfloat16*)alloc(8388608);       // attn context
  __hip_bfloat16* part  = (__hip_bfloat16*)alloc(4u * 8388608);  // bf16 partials (<=4)
  float*          x1f   = (float*)alloc(16777216);               // LN1 out f32
  __hip_bfloat16* x1b   = (__hip_bfloat16*)alloc(8388608);       // LN1 out bf16
  __hip_bfloat16* hb    = (__hip_bfloat16*)alloc(33554432);      // gelu(ffn1)
  (void)ws_size; (void)in_sizes; (void)n_in; (void)out_size;

  // 0. single-launch cast of x + all weights to bf16
  cast_all_kernel<<<16384, 256, 0, stream>>>(x, xb, 4096,
                                             Wqkv, wqkvb, 3072,
                                             Wo, wob, 1024,
                                             W1, w1b, 4096,
                                             W2, w2b);
  // 1. QKV projection
  gemm_bt<0><<<dim3(24, 32), 256, 0, stream>>>(xb, wqkvb, bqkv, qkvb, 4096, 3072, 1024);
  // 2. attention
  transpose_v_kernel<<<dim3(16, 64), 256, 0, stream>>>(qkvb, vtb);
  attn_kernel<<<1024, 256, 0, stream>>>(qkvb, vtb, ctxb);
  // 3. output projection (split-K=2) + fused reduce+resid+LN1
  gemm_bt_splitk<<<dim3(8, 32, 2), 256, 0, stream>>>(ctxb, wob, part, 4096, 1024, 1024, 512);
  ln_sum_kernel<2, 1><<<4096, 256, 0, stream>>>(part, x, bo, g1, be1, x1f, x1b);
  // 4. FFN
  gemm_bt<1><<<dim3(32, 32), 256, 0, stream>>>(x1b, w1b, b1, hb, 4096, 4096, 1024);
  gemm_bt_splitk<<<dim3(8, 32, 4), 256, 0, stream>>>(hb, w2b, part, 4096, 1024, 4096, 1024);
  ln_sum_kernel<4, 0><<<4096, 256, 0, stream>>>(part, x1f, b2, g2, be2, (float*)d_out, nullptr);
}

// Round 8
// 354.416 us; speedup vs baseline: 1.1889x; 1.0138x over previous
//
#include <hip/hip_runtime.h>
#include <hip/hip_bf16.h>

typedef __attribute__((ext_vector_type(4))) float floatx4;
typedef __attribute__((ext_vector_type(8))) short shortx8;

struct bf4 { __hip_bfloat16 h[4]; };
union U8 { shortx8 v; __hip_bfloat16 h[8]; };
union U4 { unsigned long long v; __hip_bfloat16 h[4]; };

__device__ __forceinline__ void async_copy16(const __hip_bfloat16* g, __hip_bfloat16* l) {
  __builtin_amdgcn_global_load_lds((__attribute__((address_space(1))) void*)g,
                                   (__attribute__((address_space(3))) void*)l,
                                   16, 0, 0);
}

// ---------------------------------------------------------------------------
// One-launch fp32 -> bf16 cast over 5 ranges (x, Wqkv, Wo, W1, W2).
// ---------------------------------------------------------------------------
__global__ __launch_bounds__(256) void cast_all_kernel(
    const float* __restrict__ s0, __hip_bfloat16* __restrict__ d0, int nb0,
    const float* __restrict__ s1, __hip_bfloat16* __restrict__ d1, int nb1,
    const float* __restrict__ s2, __hip_bfloat16* __restrict__ d2, int nb2,
    const float* __restrict__ s3, __hip_bfloat16* __restrict__ d3, int nb3,
    const float* __restrict__ s4, __hip_bfloat16* __restrict__ d4) {
  int b = blockIdx.x;
  const float* src; __hip_bfloat16* dst;
  if (b < nb0) { src = s0; dst = d0; }
  else { b -= nb0;
    if (b < nb1) { src = s1; dst = d1; }
    else { b -= nb1;
      if (b < nb2) { src = s2; dst = d2; }
      else { b -= nb2;
        if (b < nb3) { src = s3; dst = d3; }
        else { b -= nb3; src = s4; dst = d4; }
      }
    }
  }
  const int i = b * 256 + threadIdx.x;
  const float4 v = ((const float4*)src)[i];
  bf4 o4;
  o4.h[0] = __float2bfloat16(v.x);
  o4.h[1] = __float2bfloat16(v.y);
  o4.h[2] = __float2bfloat16(v.z);
  o4.h[3] = __float2bfloat16(v.w);
  *(bf4*)(dst + (size_t)i * 4) = o4;
}

// XCD swizzle (round 6): each XCD owns a disjoint 4-M-tile stripe.
#define GEMM_SWIZZLE()                                                        \
  const int flat = blockIdx.x + gridDim.x * (blockIdx.y + 32 * blockIdx.z);   \
  const int xcd_ = flat & 7;                                                  \
  int rsw_ = flat >> 3;                                                       \
  const int mt_ = xcd_ * 4 + (rsw_ & 3);                                      \
  rsw_ >>= 2;                                                                 \
  const int nt_ = rsw_ % gridDim.x;                                           \
  const int zt_ = rsw_ / gridDim.x;

// Depth-2 pipelined K-loop (round 7): THREE LDS buffers; iter k issues
// stage(k+2) then waits vmcnt(8) -> the awaited loads (iter k's) are ~2
// iterations (~900+ cyc) old, matching HBM latency (m126), instead of the
// depth-1 scheme's ~450 cyc. Buffer b read at iter k is next overwritten by
// stage(k+3), issued after iter k's trailing barrier -> race-free.
// LDS chunk swizzle (round 4, verified conflicts=0).
#define GEMM_STAGE(buf, koff)                                      \
  async_copy16(Ag0 + (koff),           &As[buf][tid * 8]);         \
  async_copy16(Ag0 + (koff) + rstride, &As[buf][tid * 8 + 2048]);  \
  async_copy16(Bg0 + (koff),           &Bs[buf][tid * 8]);         \
  async_copy16(Bg0 + (koff) + rstride, &Bs[buf][tid * 8 + 2048]);

#define GEMM_KLOOP(NI)                                                        \
  GEMM_STAGE(0, 0)                                                            \
  GEMM_STAGE(1, 32)                                                           \
  int cur = 0;                                                                \
  for (int it = 0; it < (NI); ++it) {                                         \
    if (it + 2 < (NI)) {                                                      \
      const int nb = (cur >= 1) ? cur - 1 : cur + 2;  /* (cur+2)%3 */         \
      GEMM_STAGE(nb, (it + 2) * 32)                                           \
      asm volatile("s_waitcnt vmcnt(8)" ::: "memory");                        \
    } else if (it + 1 < (NI)) {                                               \
      asm volatile("s_waitcnt vmcnt(4)" ::: "memory");                        \
    } else {                                                                  \
      asm volatile("s_waitcnt vmcnt(0)" ::: "memory");                        \
    }                                                                         \
    asm volatile("s_barrier" ::: "memory");                                   \
    const __hip_bfloat16* Ac = As[cur];                                       \
    const __hip_bfloat16* Bc = Bs[cur];                                       \
    shortx8 afr[4], bfr[4];                                                   \
    _Pragma("unroll")                                                         \
    for (int i = 0; i < 4; ++i) {                                             \
      afr[i] = *(const shortx8*)&Ac[(wr * 64 + i * 16 + fr) * 32 + sw];       \
      bfr[i] = *(const shortx8*)&Bc[(wc * 64 + i * 16 + fr) * 32 + sw];       \
    }                                                                         \
    _Pragma("unroll")                                                         \
    for (int mi = 0; mi < 4; ++mi)                                            \
      _Pragma("unroll")                                                       \
      for (int ni = 0; ni < 4; ++ni)                                          \
        acc[mi][ni] = __builtin_amdgcn_mfma_f32_16x16x32_bf16(                \
            afr[mi], bfr[ni], acc[mi][ni], 0, 0, 0);                          \
    asm volatile("s_barrier" ::: "memory");                                   \
    cur = (cur == 2) ? 0 : cur + 1;                                           \
  }

// ---------------------------------------------------------------------------
// GEMM C[M,N] = A[M,K] * B[N,K]^T  (bf16 in, fp32 acc), 128x128 tile
// EPI: 0 = +bias -> bf16 out; 1 = +bias, gelu(tanh form) -> bf16 out
// ---------------------------------------------------------------------------
template<int EPI>
__global__ __launch_bounds__(256) void gemm_bt(
    const __hip_bfloat16* __restrict__ A,   // [M,K]
    const __hip_bfloat16* __restrict__ B,   // [N,K]
    const float* __restrict__ bias,         // [N]
    __hip_bfloat16* __restrict__ outb,
    int M, int N, int K)
{
  __shared__ __align__(16) __hip_bfloat16 As[3][128 * 32];
  __shared__ __align__(16) __hip_bfloat16 Bs[3][128 * 32];
  const int tid  = threadIdx.x;
  const int lane = tid & 63;
  const int wave = tid >> 6;
  const int wr = wave >> 1, wc = wave & 1;
  GEMM_SWIZZLE()
  const long bm = (long)mt_ * 128, bn = (long)nt_ * 128;
  (void)zt_;

  const int srow = tid >> 2;
  const int scol = ((((tid & 3) - (tid >> 3)) & 3) << 3);   // swizzled k-chunk
  const __hip_bfloat16* Ag0 = A + (bm + srow) * (long)K + scol;
  const __hip_bfloat16* Bg0 = B + (bn + srow) * (long)K + scol;
  const long rstride = 64l * K;

  const int fr = lane & 15;
  const int fq = lane >> 4;
  const int sw = (((fq + ((fr >> 1) & 3)) & 3) << 3);       // phys chunk to read

  const floatx4 zero = {0.f, 0.f, 0.f, 0.f};
  floatx4 acc[4][4];
#pragma unroll
  for (int mi = 0; mi < 4; ++mi)
#pragma unroll
    for (int ni = 0; ni < 4; ++ni) acc[mi][ni] = zero;

  const int NI = K >> 5;
  GEMM_KLOOP(NI)

  // epilogue: C/D layout col = lane&15, row = (lane>>4)*4 + reg
#pragma unroll
  for (int mi = 0; mi < 4; ++mi) {
#pragma unroll
    for (int ni = 0; ni < 4; ++ni) {
      const long col = bn + wc * 64 + ni * 16 + fr;
      const float bv = bias[col];
#pragma unroll
      for (int r = 0; r < 4; ++r) {
        const long row = bm + wr * 64 + mi * 16 + fq * 4 + r;
        float v = acc[mi][ni][r] + bv;
        if (EPI == 1) {
          const float u = v + 0.044715f * v * v * v;
          v = v / (1.0f + __expf(-1.5957691216057308f * u));
        }
        outb[(size_t)row * N + col] = __float2bfloat16(v);
      }
    }
  }
}

// ---------------------------------------------------------------------------
// Split-K GEMM -> bf16 partials; reduce fused into ln_sum_kernel.
// ---------------------------------------------------------------------------
__global__ __launch_bounds__(256) void gemm_bt_splitk(
    const __hip_bfloat16* __restrict__ A,   // [M,K]
    const __hip_bfloat16* __restrict__ B,   // [N,K]
    __hip_bfloat16* __restrict__ part,      // [splits, M, N] bf16
    int M, int N, int K, int Klen)
{
  __shared__ __align__(16) __hip_bfloat16 As[3][128 * 32];
  __shared__ __align__(16) __hip_bfloat16 Bs[3][128 * 32];
  const int tid  = threadIdx.x;
  const int lane = tid & 63;
  const int wave = tid >> 6;
  const int wr = wave >> 1, wc = wave & 1;
  GEMM_SWIZZLE()
  const long bm = (long)mt_ * 128, bn = (long)nt_ * 128;
  const int kstart = zt_ * Klen;

  const int srow = tid >> 2;
  const int scol = ((((tid & 3) - (tid >> 3)) & 3) << 3);
  const __hip_bfloat16* Ag0 = A + (bm + srow) * (long)K + kstart + scol;
  const __hip_bfloat16* Bg0 = B + (bn + srow) * (long)K + kstart + scol;
  const long rstride = 64l * K;

  const int fr = lane & 15;
  const int fq = lane >> 4;
  const int sw = (((fq + ((fr >> 1) & 3)) & 3) << 3);

  const floatx4 zero = {0.f, 0.f, 0.f, 0.f};
  floatx4 acc[4][4];
#pragma unroll
  for (int mi = 0; mi < 4; ++mi)
#pragma unroll
    for (int ni = 0; ni < 4; ++ni) acc[mi][ni] = zero;

  const int NI = Klen >> 5;
  GEMM_KLOOP(NI)

  __hip_bfloat16* outp = part + (size_t)zt_ * M * N;
#pragma unroll
  for (int mi = 0; mi < 4; ++mi) {
#pragma unroll
    for (int ni = 0; ni < 4; ++ni) {
      const long col = bn + wc * 64 + ni * 16 + fr;
#pragma unroll
      for (int r = 0; r < 4; ++r) {
        const long row = bm + wr * 64 + mi * 16 + fq * 4 + r;
        outp[(size_t)row * N + col] = __float2bfloat16(acc[mi][ni][r]);
      }
    }
  }
}

// ---------------------------------------------------------------------------
// V transpose: qkv v-part [token, h*64+d] -> vt[(bh*64+d)*1024 + token]
// ---------------------------------------------------------------------------
__global__ __launch_bounds__(256) void transpose_v_kernel(
    const __hip_bfloat16* __restrict__ qkv, __hip_bfloat16* __restrict__ vt)
{
  const int bh = blockIdx.y;
  const int tt = blockIdx.x;
  const int b = bh >> 4, h = bh & 15;
  __shared__ __hip_bfloat16 tile[64][65];
  const int tid = threadIdx.x;
  const int r = tid >> 2;
  const int c = (tid & 3) << 4;
  const __hip_bfloat16* src = qkv + (size_t)(b * 1024 + tt * 64 + r) * 3072 + 2048 + h * 64 + c;
  U8 u0, u1;
  u0.v = *(const shortx8*)src;
  u1.v = *(const shortx8*)(src + 8);
#pragma unroll
  for (int j = 0; j < 8; ++j) { tile[r][c + j] = u0.h[j]; tile[r][c + 8 + j] = u1.h[j]; }
  __syncthreads();
  U8 w0, w1;
#pragma unroll
  for (int j = 0; j < 8; ++j) { w0.h[j] = tile[c + j][r]; w1.h[j] = tile[c + 8 + j][r]; }
  __hip_bfloat16* dst = vt + ((size_t)bh * 64 + r) * 1024 + tt * 64 + c;
  *(shortx8*)dst       = w0.v;
  *(shortx8*)(dst + 8) = w1.v;
}

// ---------------------------------------------------------------------------
// Banded-causal flash attention. One wave per (b,h,q-tile of 16).
// ---------------------------------------------------------------------------
__global__ __launch_bounds__(256) void attn_kernel(
    const __hip_bfloat16* __restrict__ qkv,
    const __hip_bfloat16* __restrict__ vt,
    __hip_bfloat16* __restrict__ ctx)
{
  const int wave = threadIdx.x >> 6;
  const int lane = threadIdx.x & 63;
  const int gw = blockIdx.x * 4 + wave;
  const int qt = gw & 63;
  const int bh = gw >> 6;
  const int b = bh >> 4, h = bh & 15;
  const int fr = lane & 15, fq = lane >> 4;
  const int q0 = qt << 4;

  __shared__ __align__(16) __hip_bfloat16 Plds[4][16 * 32];
  __hip_bfloat16* Pw = Plds[wave];

  const __hip_bfloat16* qrow = qkv + (size_t)(b * 1024 + q0 + fr) * 3072 + h * 64;
  const shortx8 aq0 = *(const shortx8*)(qrow + fq * 8);
  const shortx8 aq1 = *(const shortx8*)(qrow + 32 + fq * 8);

  const float SC = 0.125f * 1.44269504088896f;
  float m_r[4] = {-1e30f, -1e30f, -1e30f, -1e30f};
  float l_r[4] = {0.f, 0.f, 0.f, 0.f};
  const floatx4 zero = {0.f, 0.f, 0.f, 0.f};
  floatx4 o[4];
#pragma unroll
  for (int nd = 0; nd < 4; ++nd) o[nd] = zero;

  const int kt0 = (q0 >= 255) ? ((q0 - 255) >> 5) : 0;
  const int kt1 = (q0 + 15) >> 5;
  for (int kt = kt0; kt <= kt1; ++kt) {
    const int kbase = kt << 5;
    const __hip_bfloat16* krow0 = qkv + (size_t)(b * 1024 + kbase + fr) * 3072 + 1024 + h * 64;
    const __hip_bfloat16* krow1 = krow0 + 16 * 3072;
    const shortx8 bk00 = *(const shortx8*)(krow0 + fq * 8);
    const shortx8 bk01 = *(const shortx8*)(krow0 + 32 + fq * 8);
    const shortx8 bk10 = *(const shortx8*)(krow1 + fq * 8);
    const shortx8 bk11 = *(const shortx8*)(krow1 + 32 + fq * 8);
    floatx4 s0 = zero, s1 = zero;
    s0 = __builtin_amdgcn_mfma_f32_16x16x32_bf16(aq0, bk00, s0, 0, 0, 0);
    s0 = __builtin_amdgcn_mfma_f32_16x16x32_bf16(aq1, bk01, s0, 0, 0, 0);
    s1 = __builtin_amdgcn_mfma_f32_16x16x32_bf16(aq0, bk10, s1, 0, 0, 0);
    s1 = __builtin_amdgcn_mfma_f32_16x16x32_bf16(aq1, bk11, s1, 0, 0, 0);
#pragma unroll
    for (int r = 0; r < 4; ++r) { s0[r] *= SC; s1[r] *= SC; }
    if (kbase + 31 > q0 || kbase < q0 - 240) {
#pragma unroll
      for (int r = 0; r < 4; ++r) {
        const int tq = q0 + fq * 4 + r;
        const int j0 = kbase + fr;
        const int j1 = j0 + 16;
        if (j0 > tq || j0 < tq - 255) s0[r] = -3e38f;
        if (j1 > tq || j1 < tq - 255) s1[r] = -3e38f;
      }
    }
#pragma unroll
    for (int r = 0; r < 4; ++r) {
      float vmax = fmaxf(s0[r], s1[r]);
      vmax = fmaxf(vmax, __shfl_xor(vmax, 1));
      vmax = fmaxf(vmax, __shfl_xor(vmax, 2));
      vmax = fmaxf(vmax, __shfl_xor(vmax, 4));
      vmax = fmaxf(vmax, __shfl_xor(vmax, 8));
      const float mnew = fmaxf(m_r[r], vmax);
      const float alpha = exp2f(m_r[r] - mnew);
      const float p0 = exp2f(s0[r] - mnew);
      const float p1 = exp2f(s1[r] - mnew);
      m_r[r] = mnew;
      float ps = p0 + p1;
      ps += __shfl_xor(ps, 1);
      ps += __shfl_xor(ps, 2);
      ps += __shfl_xor(ps, 4);
      ps += __shfl_xor(ps, 8);
      l_r[r] = l_r[r] * alpha + ps;
      o[0][r] *= alpha; o[1][r] *= alpha; o[2][r] *= alpha; o[3][r] *= alpha;
      Pw[(fq * 4 + r) * 32 + fr]      = __float2bfloat16(p0);
      Pw[(fq * 4 + r) * 32 + 16 + fr] = __float2bfloat16(p1);
    }
    asm volatile("s_waitcnt lgkmcnt(0)" ::: "memory");
    const shortx8 ap = *(const shortx8*)&Pw[fr * 32 + fq * 8];
#pragma unroll
    for (int nd = 0; nd < 4; ++nd) {
      const shortx8 bv = *(const shortx8*)&vt[((size_t)bh * 64 + nd * 16 + fr) * 1024 + kbase + fq * 8];
      o[nd] = __builtin_amdgcn_mfma_f32_16x16x32_bf16(ap, bv, o[nd], 0, 0, 0);
    }
    asm volatile("s_waitcnt lgkmcnt(0)" ::: "memory");
  }
#pragma unroll
  for (int nd = 0; nd < 4; ++nd)
#pragma unroll
    for (int r = 0; r < 4; ++r)
      ctx[(size_t)(b * 1024 + q0 + fq * 4 + r) * 1024 + h * 64 + nd * 16 + fr] =
          __float2bfloat16(o[nd][r] / l_r[r]);
}

// ---------------------------------------------------------------------------
// Fused split-K reduce (bf16 partials) + bias + residual + LayerNorm.
// ---------------------------------------------------------------------------
template<int S, int WB>
__global__ __launch_bounds__(256) void ln_sum_kernel(
    const __hip_bfloat16* __restrict__ part,  // [S, 4096, 1024] bf16
    const float* __restrict__ resid,          // [4096, 1024]
    const float* __restrict__ bias,           // [1024]
    const float* __restrict__ g, const float* __restrict__ be,
    float* __restrict__ outf, __hip_bfloat16* __restrict__ outb)
{
  const int row = blockIdx.x;
  const int tid = threadIdx.x;
  const size_t base = (size_t)row * 1024;
  float4 v = ((const float4*)(resid + base))[tid];
  const float4 bv = ((const float4*)bias)[tid];
  v.x += bv.x; v.y += bv.y; v.z += bv.z; v.w += bv.w;
#pragma unroll
  for (int s = 0; s < S; ++s) {
    U4 p;
    p.v = *(const unsigned long long*)&part[(size_t)s * 4096 * 1024 + base + tid * 4];
    v.x += __bfloat162float(p.h[0]);
    v.y += __bfloat162float(p.h[1]);
    v.z += __bfloat162float(p.h[2]);
    v.w += __bfloat162float(p.h[3]);
  }
  float sm = v.x + v.y + v.z + v.w;
  float ss = v.x * v.x + v.y * v.y + v.z * v.z + v.w * v.w;
#pragma unroll
  for (int off = 1; off < 64; off <<= 1) {
    sm += __shfl_xor(sm, off);
    ss += __shfl_xor(ss, off);
  }
  __shared__ float red[8];
  if ((tid & 63) == 0) { red[tid >> 6] = sm; red[4 + (tid >> 6)] = ss; }
  __syncthreads();
  sm = red[0] + red[1] + red[2] + red[3];
  ss = red[4] + red[5] + red[6] + red[7];
  const float mu = sm * (1.0f / 1024.0f);
  const float rs = rsqrtf(ss * (1.0f / 1024.0f) - mu * mu + 1e-5f);
  const float4 gg = ((const float4*)g)[tid];
  const float4 bb = ((const float4*)be)[tid];
  float4 y;
  y.x = (v.x - mu) * rs * gg.x + bb.x;
  y.y = (v.y - mu) * rs * gg.y + bb.y;
  y.z = (v.z - mu) * rs * gg.z + bb.z;
  y.w = (v.w - mu) * rs * gg.w + bb.w;
  ((float4*)(outf + base))[tid] = y;
  if (WB) {
    bf4 o4;
    o4.h[0] = __float2bfloat16(y.x);
    o4.h[1] = __float2bfloat16(y.y);
    o4.h[2] = __float2bfloat16(y.z);
    o4.h[3] = __float2bfloat16(y.w);
    *(bf4*)(outb + base + tid * 4) = o4;
  }
}

// ---------------------------------------------------------------------------
extern "C" void kernel_launch(void* const* d_in, const int* in_sizes, int n_in,
                              void* d_out, int out_size, void* d_ws, size_t ws_size,
                              hipStream_t stream) {
  const float* x    = (const float*)d_in[0];
  const float* Wqkv = (const float*)d_in[1];
  const float* bqkv = (const float*)d_in[2];
  const float* Wo   = (const float*)d_in[3];
  const float* bo   = (const float*)d_in[4];
  const float* W1   = (const float*)d_in[5];
  const float* b1   = (const float*)d_in[6];
  const float* W2   = (const float*)d_in[7];
  const float* b2   = (const float*)d_in[8];
  const float* g1   = (const float*)d_in[9];
  const float* be1  = (const float*)d_in[10];
  const float* g2   = (const float*)d_in[11];
  const float* be2  = (const float*)d_in[12];

  char* ws = (char*)d_ws;
  size_t off = 0;
  auto alloc = [&](size_t bytes) -> void* {
    void* p = ws + off;
    off += (bytes + 255) & ~(size_t)255;
    return p;
  };
  __hip_bfloat16* wqkvb = (__hip_bfloat16*)alloc(6291456);
  __hip_bfloat16* wob   = (__hip_bfloat16*)alloc(2097152);
  __hip_bfloat16* w1b   = (__hip_bfloat16*)alloc(8388608);
  __hip_bfloat16* w2b   = (__hip_bfloat16*)alloc(8388608);
  __hip_bfloat16* xb    = (__hip_bfloat16*)alloc(8388608);
  __hip_bfloat16* qkvb  = (__hip_bfloat16*)alloc(25165824);
  __hip_bfloat16* vtb   = (__hip_bfloat16*)alloc(8388608);
  __hip_bfloat16* ctxb  = (__hip_bfloat16*)alloc(8388608);
  __hip_bfloat16* part  = (__hip_bfloat16*)alloc(4u * 8388608);
  float*          x1f   = (float*)alloc(16777216);
  __hip_bfloat16* x1b   = (__hip_bfloat16*)alloc(8388608);
  __hip_bfloat16* hb    = (__hip_bfloat16*)alloc(33554432);
  (void)ws_size; (void)in_sizes; (void)n_in; (void)out_size;

  // 0. single-launch cast of x + all weights to bf16
  cast_all_kernel<<<16384, 256, 0, stream>>>(x, xb, 4096,
                                             Wqkv, wqkvb, 3072,
                                             Wo, wob, 1024,
                                             W1, w1b, 4096,
                                             W2, w2b);
  // 1. QKV projection
  gemm_bt<0><<<dim3(24, 32), 256, 0, stream>>>(xb, wqkvb, bqkv, qkvb, 4096, 3072, 1024);
  // 2. attention
  transpose_v_kernel<<<dim3(16, 64), 256, 0, stream>>>(qkvb, vtb);
  attn_kernel<<<1024, 256, 0, stream>>>(qkvb, vtb, ctxb);
  // 3. output projection (split-K=2) + fused reduce+resid+LN1
  gemm_bt_splitk<<<dim3(8, 32, 2), 256, 0, stream>>>(ctxb, wob, part, 4096, 1024, 1024, 512);
  ln_sum_kernel<2, 1><<<4096, 256, 0, stream>>>(part, x, bo, g1, be1, x1f, x1b);
  // 4. FFN
  gemm_bt<1><<<dim3(32, 32), 256, 0, stream>>>(x1b, w1b, b1, hb, 4096, 4096, 1024);
  gemm_bt_splitk<<<dim3(8, 32, 4), 256, 0, stream>>>(hb, w2b, part, 4096, 1024, 4096, 1024);
  ln_sum_kernel<4, 0><<<4096, 256, 0, stream>>>(part, x1f, b2, g2, be2, (float*)d_out, nullptr);
}